// Round 2
// baseline (655.915 us; speedup 1.0000x reference)
//
#include <hip/hip_runtime.h>
#include <hip/hip_bf16.h>

typedef __attribute__((ext_vector_type(4))) float f32x4;
typedef __attribute__((ext_vector_type(8))) short short8;

__device__ __forceinline__ float bf2f(unsigned short u){
  union { unsigned u32; float f; } v; v.u32 = ((unsigned)u) << 16; return v.f;
}
__device__ __forceinline__ unsigned short f2bf(float f){
  union { float f; unsigned u; } v; v.f = f;
  unsigned x = v.u;
  unsigned r = x + 0x7fffu + ((x >> 16) & 1u);
  return (unsigned short)(r >> 16);
}
__device__ __forceinline__ short8 pack8(f32x4 a, f32x4 b){
  short8 r;
  r[0]=(short)f2bf(a[0]); r[1]=(short)f2bf(a[1]);
  r[2]=(short)f2bf(a[2]); r[3]=(short)f2bf(a[3]);
  r[4]=(short)f2bf(b[0]); r[5]=(short)f2bf(b[1]);
  r[6]=(short)f2bf(b[2]); r[7]=(short)f2bf(b[3]);
  return r;
}

// async global->LDS, 16B per lane. LDS dest is wave-uniform base + lane*16.
__device__ __forceinline__ void gload_lds16(const unsigned short* g, unsigned short* l) {
  __builtin_amdgcn_global_load_lds(
      (const __attribute__((address_space(1))) unsigned int*)g,
      (__attribute__((address_space(3))) unsigned int*)l, 16, 0, 0);
}

// ---------------------------------------------------------------------------
// K0: tiny prep — ball[96], aall[96] (row order: 0..15 q (h*4+o), 16..31 k,
// 32..95 v (h*16+o)), Wps[c][o] = Wp[o][c].
// ---------------------------------------------------------------------------
__global__ __launch_bounds__(256) void prep_kernel(
    const float* bq, const float* aq, const float* bk, const float* ak,
    const float* bv, const float* av, const float* Wp,
    float* ball, float* aall, float* Wps)
{
  int idx = blockIdx.x * 256 + threadIdx.x;
  if (idx < 96) {
    int j = idx;
    float b, a;
    if (j < 16)      { b = bq[j];      a = aq[j >> 2]; }
    else if (j < 32) { b = bk[j - 16]; a = ak[(j - 16) >> 2]; }
    else             { b = bv[j - 32]; a = av[(j - 32) >> 4]; }
    ball[j] = b; aall[j] = a;
  } else if (idx < 96 + 4096) {
    int r = idx - 96; int o = r >> 6, c = r & 63;
    Wps[c * 64 + o] = Wp[o * 64 + c];
  }
}

// ---------------------------------------------------------------------------
// K1: MFMA QKV: Y[96 x (2t*128f)] = W[96x64] * X[64 x n] per (b, t-pair),
// + bias + PReLU + ChannelNorm(group over (o,f)) + gamma/beta -> bf16 out.
// Block: 256 thr (4 waves); wave w owns n in [w*64, w*64+64), tl = w>>1.
// LDS X layout: [n][c], pitch 64, c-blocks of 8 XOR-swizzled by (n>>1)&7.
// Epilogue split into two 48-row passes so the y-stash fits in the xl pool
// (peak LDS ~36.8KB -> 4 blocks/CU instead of 2).
// ---------------------------------------------------------------------------
__global__ __launch_bounds__(256, 4) void qkv_mfma(
    const float* __restrict__ x,
    const float* __restrict__ Wq, const float* __restrict__ Wk,
    const float* __restrict__ Wv,
    const float* __restrict__ ball, const float* __restrict__ aall,
    const float* __restrict__ gq, const float* __restrict__ gk,
    const float* __restrict__ gv,
    const float* __restrict__ beq, const float* __restrict__ bek,
    const float* __restrict__ bev,
    unsigned short* __restrict__ qf, unsigned short* __restrict__ kf,
    unsigned short* __restrict__ vf)
{
  __shared__ unsigned short upool[256 * 64];   // xl (32KB) then yl 48x264 (25.3KB)
  __shared__ float partS[4][96], partQ[4][96];
  __shared__ float gm[2][12], gi[2][12];
  __shared__ float bias_l[96], a_l[96];

  int tid = threadIdx.x;
  int t0 = blockIdx.x * 2, b = blockIdx.y;
  int lane = tid & 63, wave = tid >> 6;
  int l15 = lane & 15, quad = lane >> 4;

  if (tid < 96) { bias_l[tid] = ball[tid]; a_l[tid] = aall[tid]; }

  // ---- A fragments: W rows j = 16*mt + l15, k = 32*ks + quad*8 + [0..8) ----
  const float* wsrc[6] = {
    Wq + l15 * 64, Wk + l15 * 64,
    Wv + l15 * 64, Wv + (16 + l15) * 64,
    Wv + (32 + l15) * 64, Wv + (48 + l15) * 64
  };
  short8 afr[6][2];
  #pragma unroll
  for (int mt = 0; mt < 6; mt++)
    #pragma unroll
    for (int ks = 0; ks < 2; ks++) {
      const float* p = wsrc[mt] + ks * 32 + quad * 8;
      afr[mt][ks] = pack8(*(const f32x4*)p, *(const f32x4*)(p + 4));
    }

  // ---- stage X -> LDS (bf16, transposed to [n][c], swizzled) ----
  unsigned short* xl = upool;
  #pragma unroll
  for (int it = 0; it < 4; it++) {
    int item = it * 256 + tid;      // [0,1024): 8 cb x 128 np
    int cb = item >> 7;             // c-block 0..7
    int np = item & 127;            // n-pair
    int n = np * 2;
    int tl = n >> 7, f = n & 127;
    const float* gp = x + ((long)(b * 64 + cb * 8) * 1024 + t0 + tl) * 128 + f;
    short8 lo, hi;
    #pragma unroll
    for (int w = 0; w < 8; w++) {
      float2 v = *(const float2*)(gp + (long)w * 131072);
      lo[w] = (short)f2bf(v.x);
      hi[w] = (short)f2bf(v.y);
    }
    int perm = cb ^ (np & 7);       // key = (n>>1)&7, same for n and n+1
    *(short8*)&xl[n * 64 + perm * 8]       = lo;
    *(short8*)&xl[(n + 1) * 64 + perm * 8] = hi;
  }
  __syncthreads();

  // ---- MFMA: acc[mt][nt] = W-tile x X-tile ----
  f32x4 acc[6][4];
  #pragma unroll
  for (int mt = 0; mt < 6; mt++)
    #pragma unroll
    for (int nt = 0; nt < 4; nt++)
      acc[mt][nt] = {0.f, 0.f, 0.f, 0.f};

  int nb = wave * 64;
  #pragma unroll
  for (int ks = 0; ks < 2; ks++)
    #pragma unroll
    for (int nt = 0; nt < 4; nt++) {
      int n = nb + nt * 16 + l15;
      int perm = (ks * 4 + quad) ^ ((n >> 1) & 7);
      short8 bfrag = *(const short8*)&xl[n * 64 + perm * 8];
      #pragma unroll
      for (int mt = 0; mt < 6; mt++)
        acc[mt][nt] = __builtin_amdgcn_mfma_f32_16x16x32_bf16(
            afr[mt][ks], bfrag, acc[mt][nt], 0, 0, 0);
    }

  // ---- bias + PReLU, then per-row partial sums over this wave's 64 cols ----
  #pragma unroll
  for (int mt = 0; mt < 6; mt++)
    #pragma unroll
    for (int r = 0; r < 4; r++) {
      int j = mt * 16 + quad * 4 + r;
      float bb = bias_l[j], aa = a_l[j];
      #pragma unroll
      for (int nt = 0; nt < 4; nt++) {
        float v = acc[mt][nt][r] + bb;
        acc[mt][nt][r] = v > 0.f ? v : aa * v;
      }
      float s  = acc[mt][0][r] + acc[mt][1][r] + acc[mt][2][r] + acc[mt][3][r];
      float q2 = acc[mt][0][r]*acc[mt][0][r] + acc[mt][1][r]*acc[mt][1][r]
               + acc[mt][2][r]*acc[mt][2][r] + acc[mt][3][r]*acc[mt][3][r];
      #pragma unroll
      for (int m = 1; m <= 8; m <<= 1) {
        s  += __shfl_xor(s,  m, 64);
        q2 += __shfl_xor(q2, m, 64);
      }
      if (l15 == 0) { partS[wave][j] = s; partQ[wave][j] = q2; }
    }
  __syncthreads();   // xl reads done everywhere; partS/Q complete

  // ---- group stats (needs only partS/partQ) ----
  if (tid < 24) {
    int g = tid % 12, tl2 = tid / 12;
    int r0 = (g < 4) ? g * 4 : (g < 8) ? 16 + (g - 4) * 4 : 32 + (g - 8) * 16;
    int nr = (g < 8) ? 4 : 16;
    float S = 0.f, Q = 0.f;
    for (int w = tl2 * 2; w < tl2 * 2 + 2; w++)
      for (int r = 0; r < nr; r++) { S += partS[w][r0 + r]; Q += partQ[w][r0 + r]; }
    float cnt = (float)(nr * 128);
    float mean = S / cnt;
    float var = fmaxf(Q / cnt - mean * mean, 0.f);
    gm[tl2][g] = mean;
    gi[tl2][g] = rsqrtf(var + 1e-5f);
  }

  // ---- two-pass epilogue: stash 48 rows as bf16, normalize, store; repeat --
  unsigned short* yl = upool;   // 48 rows, pitch 264 (25.3KB; fits xl pool)
  int ch = tid & 31, jrow = tid >> 5;

  #pragma unroll
  for (int half = 0; half < 2; half++) {
    int jbase = half * 48;
    // stash this half's rows (mt = 3*half .. 3*half+2)
    #pragma unroll
    for (int mt3 = 0; mt3 < 3; mt3++) {
      int mt = half * 3 + mt3;
      #pragma unroll
      for (int nt = 0; nt < 4; nt++) {
        int n = nb + nt * 16 + l15;
        #pragma unroll
        for (int r = 0; r < 4; r++) {
          int jrel = mt3 * 16 + quad * 4 + r;
          yl[jrel * 264 + n] = f2bf(acc[mt][nt][r]);
        }
      }
    }
    __syncthreads();   // yl half ready (and gm/gi ready on first pass)

    #pragma unroll
    for (int itj = 0; itj < 6; itj++) {
      int j = jbase + itj * 8 + jrow;
      int n0 = ch * 8;
      int tl3 = n0 >> 7, f = n0 & 127;
      short8 y8 = *(const short8*)&yl[(j - jbase) * 264 + n0];
      int g = (j < 16) ? (j >> 2) : (j < 32) ? 4 + ((j - 16) >> 2) : 8 + ((j - 32) >> 4);
      float mean = gm[tl3][g], inv = gi[tl3][g];
      const float *gsrc, *bsrc;
      int jo;
      unsigned short* dst;
      if (j < 16) {
        jo = j; gsrc = gq; bsrc = beq;
        int h = j >> 2, o = j & 3;
        dst = qf + (((long)(h * 4 + b) * 1024 + t0 + tl3) * 512 + o * 128 + f);
      } else if (j < 32) {
        jo = j - 16; gsrc = gk; bsrc = bek;
        int h = jo >> 2, o = jo & 3;
        dst = kf + (((long)(h * 4 + b) * 1024 + t0 + tl3) * 512 + o * 128 + f);
      } else {
        jo = j - 32; gsrc = gv; bsrc = bev;
        int h = jo >> 4, o = jo & 15;
        dst = vf + (((long)(h * 4 + b) * 1024 + t0 + tl3) * 2048 + o * 128 + f);
      }
      f32x4 g0 = *(const f32x4*)(gsrc + jo * 128 + f);
      f32x4 g1 = *(const f32x4*)(gsrc + jo * 128 + f + 4);
      f32x4 b0 = *(const f32x4*)(bsrc + jo * 128 + f);
      f32x4 b1 = *(const f32x4*)(bsrc + jo * 128 + f + 4);
      short8 o8;
      #pragma unroll
      for (int i = 0; i < 4; i++) {
        o8[i]     = (short)f2bf((bf2f((unsigned short)y8[i])     - mean) * inv * g0[i] + b0[i]);
        o8[i + 4] = (short)f2bf((bf2f((unsigned short)y8[i + 4]) - mean) * inv * g1[i] + b1[i]);
      }
      *(short8*)dst = o8;
    }
    if (half == 0) __syncthreads();   // yl reads done before overwriting
  }
}

// ---------------------------------------------------------------------------
// K2: transpose vf[n][t][dv] -> vfT[n][dv][t]  (64x64 tiles via LDS, bf16)
// ---------------------------------------------------------------------------
__global__ __launch_bounds__(256) void transpose_v(
    const unsigned short* __restrict__ vf, unsigned short* __restrict__ vfT)
{
  __shared__ unsigned short tile[64][65];
  int n = blockIdx.z;
  int d0 = blockIdx.x * 64, t0 = blockIdx.y * 64;
  int tid = threadIdx.x;
  int cr = tid >> 4, cc = (tid & 15) * 4;

  const unsigned short* src = vf + ((long)n * 1024 + t0) * 2048 + d0;
  #pragma unroll
  for (int i = 0; i < 4; i++) {
    int r = cr + i * 16;   // t-local
    ushort4 u = *(const ushort4*)(src + (long)r * 2048 + cc);
    tile[r][cc + 0] = u.x; tile[r][cc + 1] = u.y;
    tile[r][cc + 2] = u.z; tile[r][cc + 3] = u.w;
  }
  __syncthreads();
  unsigned short* dst = vfT + ((long)n * 2048 + d0) * 1024 + t0;
  #pragma unroll
  for (int i = 0; i < 4; i++) {
    int r = cr + i * 16;   // d-local
    ushort4 u;
    u.x = tile[cc + 0][r]; u.y = tile[cc + 1][r];
    u.z = tile[cc + 2][r]; u.w = tile[cc + 3][r];
    *(ushort4*)(dst + (long)r * 1024 + cc) = u;
  }
}

// ---------------------------------------------------------------------------
// K3: batched GEMM, D[m][n] = scale * sum_k A[m][k]*B[n][k]  (both k-contig)
// 128x128 tile, BK=32, 4 waves each 64x64 via 16 MFMA (16x16x32 bf16).
// m97 structure: global_load_lds dwordx4 into linear [128][32]-ushort LDS.
// Bank-conflict-free chunk swizzle key is (row>>1)&3: slot within the row's
// 64B = quad ^ ((row>>1)&3); combined with row parity this makes every 8
// consecutive lanes of a ds_read_b128 cover all 32 banks exactly once.
// Source chunk is pre-swizzled with the same involution (m173 pattern).
// XCD-aware bijective block swizzle (nwg%8==0).
// mode 0: Cb[z][m][n] bf16 row-major.  mode 1: fp32 scatter to Cf (b,c,t,f).
// ---------------------------------------------------------------------------
__global__ __launch_bounds__(256) void gemm_bt(
    const unsigned short* __restrict__ A, const unsigned short* __restrict__ B,
    unsigned short* __restrict__ Cb, float* __restrict__ Cf,
    int M, int N, int K, long sA, long sB, long sC, float scale, int mode)
{
  __shared__ unsigned short As[128 * 32];
  __shared__ unsigned short Bs[128 * 32];
  int tid = threadIdx.x;

  // ---- XCD-aware bijective swizzle of the linearized block id ----
  int gx = gridDim.x, gy = gridDim.y;
  int bid = blockIdx.x + gx * (blockIdx.y + gy * blockIdx.z);
  int nwg = gx * gy * (int)gridDim.z;     // 1024 (QK) / 2048 (PV): % 8 == 0
  int cpx = nwg >> 3;
  int tile = (bid & 7) * cpx + (bid >> 3);
  int tx = tile % gx, trem = tile / gx;
  int ty = trem % gy, z = trem / gy;

  int m0 = ty * 128, n0 = tx * 128;
  const unsigned short* Ab = A + (long)z * sA + (long)m0 * K;
  const unsigned short* Bb = B + (long)z * sB + (long)n0 * K;
  int lane = tid & 63, wave = tid >> 6;
  int wm = (wave >> 1) * 64, wn = (wave & 1) * 64;
  int l15 = lane & 15, quad = lane >> 4;

  f32x4 acc[4][4];
  #pragma unroll
  for (int i = 0; i < 4; i++)
    #pragma unroll
    for (int j = 0; j < 4; j++) acc[i][j] = {0.f, 0.f, 0.f, 0.f};

  // staging geometry: one gload_lds call per wave covers 16 rows (64 lanes x 16B
  // = 1024B = 16 x 64B rows). lane -> (row = R + lane/4, slot = lane&3);
  // source chunk is XOR-swizzled by (row>>1)&3 so ds_read lands conflict-free.
  int srow = lane >> 2;                     // row within 16-row call
  int sck  = (lane & 3) ^ ((srow >> 1) & 3);  // R%16==0 -> (row>>1)&3 == (srow>>1)&3

  for (int k0 = 0; k0 < K; k0 += 32) {
    #pragma unroll
    for (int it = 0; it < 2; it++) {
      int R = it * 64 + wave * 16;       // 4 waves x 2 calls = 128 rows
      int row = R + srow;
      gload_lds16(Ab + (long)row * K + k0 + sck * 8, &As[R * 32]);
      gload_lds16(Bb + (long)row * K + k0 + sck * 8, &Bs[R * 32]);
    }
    __syncthreads();                      // drains vmcnt before ds_read
    short8 af[4], bfr[4];
    #pragma unroll
    for (int i = 0; i < 4; i++) {
      int row = wm + i * 16 + l15;
      af[i] = *(const short8*)&As[row * 32 + (quad ^ ((row >> 1) & 3)) * 8];
    }
    #pragma unroll
    for (int j = 0; j < 4; j++) {
      int row = wn + j * 16 + l15;
      bfr[j] = *(const short8*)&Bs[row * 32 + (quad ^ ((row >> 1) & 3)) * 8];
    }
    #pragma unroll
    for (int i = 0; i < 4; i++)
      #pragma unroll
      for (int j = 0; j < 4; j++)
        acc[i][j] = __builtin_amdgcn_mfma_f32_16x16x32_bf16(af[i], bfr[j], acc[i][j], 0, 0, 0);
    __syncthreads();
  }

  if (mode == 0) {
    #pragma unroll
    for (int i = 0; i < 4; i++)
      #pragma unroll
      for (int j = 0; j < 4; j++) {
        int row = m0 + wm + i * 16 + quad * 4;
        int col = n0 + wn + j * 16 + l15;
        unsigned short* cp = Cb + (long)z * sC + (long)row * N + col;
        #pragma unroll
        for (int r = 0; r < 4; r++)
          cp[(long)r * N] = f2bf(acc[i][j][r] * scale);
      }
  } else {
    int bb = z & 3, h = z >> 2;
    #pragma unroll
    for (int i = 0; i < 4; i++)
      #pragma unroll
      for (int j = 0; j < 4; j++) {
        int row = m0 + wm + i * 16 + quad * 4;   // tq
        int col = n0 + wn + j * 16 + l15;        // dv
        int c = col >> 7, f = col & 127;
        float* cp = Cf + (((long)(bb * 64 + h * 16 + c) * 1024 + row) * 128 + f);
        #pragma unroll
        for (int r = 0; r < 4; r++)
          cp[(long)r * 128] = acc[i][j][r];
      }
  }
}

// ---------------------------------------------------------------------------
// K4: in-place row softmax on P[z][row][0..1024) (bf16, already scaled)
// ---------------------------------------------------------------------------
__global__ __launch_bounds__(256) void softmax_kernel(unsigned short* __restrict__ P)
{
  __shared__ float red[4];
  __shared__ float bmax, bsum;
  int row = blockIdx.x, z = blockIdx.y, tid = threadIdx.x;
  unsigned short* p = P + ((long)z * 1024 + row) * 1024;
  ushort4 u = *(ushort4*)(p + tid * 4);
  float v0 = bf2f(u.x), v1 = bf2f(u.y), v2 = bf2f(u.z), v3 = bf2f(u.w);

  float m = fmaxf(fmaxf(v0, v1), fmaxf(v2, v3));
  #pragma unroll
  for (int s = 1; s <= 32; s <<= 1) m = fmaxf(m, __shfl_xor(m, s, 64));
  if ((tid & 63) == 0) red[tid >> 6] = m;
  __syncthreads();
  if (tid == 0) bmax = fmaxf(fmaxf(red[0], red[1]), fmaxf(red[2], red[3]));
  __syncthreads();
  m = bmax;

  float e0 = __expf(v0 - m), e1 = __expf(v1 - m), e2 = __expf(v2 - m), e3 = __expf(v3 - m);
  float s = e0 + e1 + e2 + e3;
  #pragma unroll
  for (int k = 1; k <= 32; k <<= 1) s += __shfl_xor(s, k, 64);
  if ((tid & 63) == 0) red[tid >> 6] = s;
  __syncthreads();
  if (tid == 0) bsum = red[0] + red[1] + red[2] + red[3];
  __syncthreads();
  float inv = 1.0f / bsum;

  u.x = f2bf(e0 * inv); u.y = f2bf(e1 * inv);
  u.z = f2bf(e2 * inv); u.w = f2bf(e3 * inv);
  *(ushort4*)(p + tid * 4) = u;
}

// ---------------------------------------------------------------------------
// K5: proj (64x64) + bias + PReLU + ChannelNorm over (C,F) + gp/betap + x.
// IN-PLACE on d_out: reads its own (b,:,t,:) fp32 slice, barrier, overwrites.
// ---------------------------------------------------------------------------
__global__ __launch_bounds__(256) void proj_kernel(
    float* __restrict__ io, const float* __restrict__ Wps,
    const float* __restrict__ bp, const float* __restrict__ ap,
    const float* __restrict__ gp, const float* __restrict__ bep,
    const float* __restrict__ x)
{
  __shared__ float xl[64 * 128];
  __shared__ float wl[64 * 64];
  __shared__ float redS[4], redQ[4];
  __shared__ float smean, sinv;

  int tid = threadIdx.x;
  int t = blockIdx.x, b = blockIdx.y;

  float* src = io + ((long)(b * 64) * 1024 + t) * 128;
  #pragma unroll
  for (int i = 0; i < 8; i++) {
    int id = tid + i * 256;
    int c = id >> 5, f4 = (id & 31) * 4;
    *(f32x4*)&xl[c * 128 + f4] = *(const f32x4*)(src + (long)c * 131072 + f4);
  }
  #pragma unroll
  for (int i = 0; i < 4; i++) {
    int id = tid + i * 256;
    ((f32x4*)wl)[id] = ((const f32x4*)Wps)[id];
  }
  __syncthreads();

  int fblk = tid & 31, rblk = tid >> 5;
  int f0 = fblk * 4, r0 = rblk * 8;

  float acc[8][4];
  #pragma unroll
  for (int rr = 0; rr < 8; rr++)
    #pragma unroll
    for (int ff = 0; ff < 4; ff++) acc[rr][ff] = 0.f;

  for (int c = 0; c < 64; c++) {
    f32x4 xv = *(const f32x4*)&xl[c * 128 + f0];
    f32x4 w0 = *(const f32x4*)&wl[c * 64 + r0];
    f32x4 w1 = *(const f32x4*)&wl[c * 64 + r0 + 4];
    #pragma unroll
    for (int rr = 0; rr < 4; rr++) {
      #pragma unroll
      for (int ff = 0; ff < 4; ff++) {
        acc[rr][ff]     += w0[rr] * xv[ff];
        acc[rr + 4][ff] += w1[rr] * xv[ff];
      }
    }
  }

  float aval = ap[0];
  #pragma unroll
  for (int rr = 0; rr < 8; rr++) {
    float bb = bp[r0 + rr];
    #pragma unroll
    for (int ff = 0; ff < 4; ff++) {
      float v = acc[rr][ff] + bb;
      acc[rr][ff] = v > 0.f ? v : aval * v;
    }
  }

  float s = 0.f, sq = 0.f;
  #pragma unroll
  for (int rr = 0; rr < 8; rr++)
    #pragma unroll
    for (int ff = 0; ff < 4; ff++) { s += acc[rr][ff]; sq += acc[rr][ff] * acc[rr][ff]; }
  #pragma unroll
  for (int m = 1; m <= 32; m <<= 1) { s += __shfl_xor(s, m, 64); sq += __shfl_xor(sq, m, 64); }
  if ((tid & 63) == 0) { redS[tid >> 6] = s; redQ[tid >> 6] = sq; }
  __syncthreads();
  if (tid == 0) {
    float S = redS[0] + redS[1] + redS[2] + redS[3];
    float Q = redQ[0] + redQ[1] + redQ[2] + redQ[3];
    float mean = S / 8192.0f;
    float var = fmaxf(Q / 8192.0f - mean * mean, 0.f);
    smean = mean; sinv = rsqrtf(var + 1e-5f);
  }
  __syncthreads();
  float mean = smean, inv = sinv;

  const float* xb = x + ((long)(b * 64) * 1024 + t) * 128;
  #pragma unroll
  for (int rr = 0; rr < 8; rr++) {
    int c = r0 + rr;
    f32x4 g4 = *(const f32x4*)(gp + c * 128 + f0);
    f32x4 b4 = *(const f32x4*)(bep + c * 128 + f0);
    f32x4 x4 = *(const f32x4*)(xb + (long)c * 131072 + f0);
    f32x4 o;
    o[0] = (acc[rr][0] - mean) * inv * g4[0] + b4[0] + x4[0];
    o[1] = (acc[rr][1] - mean) * inv * g4[1] + b4[1] + x4[1];
    o[2] = (acc[rr][2] - mean) * inv * g4[2] + b4[2] + x4[2];
    o[3] = (acc[rr][3] - mean) * inv * g4[3] + b4[3] + x4[3];
    *(f32x4*)(io + ((long)(b * 64 + c) * 1024 + t) * 128 + f0) = o;
  }
}

// ---------------------------------------------------------------------------
extern "C" void kernel_launch(void* const* d_in, const int* in_sizes, int n_in,
                              void* d_out, int out_size, void* d_ws, size_t ws_size,
                              hipStream_t stream)
{
  const float* x   = (const float*)d_in[0];
  const float* Wq  = (const float*)d_in[1];
  const float* bq  = (const float*)d_in[2];
  const float* aq  = (const float*)d_in[3];
  const float* gq  = (const float*)d_in[4];
  const float* beq = (const float*)d_in[5];
  const float* Wk  = (const float*)d_in[6];
  const float* bk  = (const float*)d_in[7];
  const float* ak  = (const float*)d_in[8];
  const float* gk  = (const float*)d_in[9];
  const float* bek = (const float*)d_in[10];
  const float* Wv  = (const float*)d_in[11];
  const float* bv  = (const float*)d_in[12];
  const float* av  = (const float*)d_in[13];
  const float* gv  = (const float*)d_in[14];
  const float* bev = (const float*)d_in[15];
  const float* Wp  = (const float*)d_in[16];
  const float* bp  = (const float*)d_in[17];
  const float* ap  = (const float*)d_in[18];
  const float* gp  = (const float*)d_in[19];
  const float* bep = (const float*)d_in[20];
  float* out = (float*)d_out;

  char* ws = (char*)d_ws;
  size_t off = 0;
  auto alloc = [&](size_t n) { size_t o = off; off += (n + 255) & ~(size_t)255; return o; };

  float* ball = (float*)(ws + alloc(96 * 4));
  float* aall = (float*)(ws + alloc(96 * 4));
  float* Wps  = (float*)(ws + alloc(4096 * 4));
  unsigned short* qf  = (unsigned short*)(ws + alloc((size_t)16 * 1024 * 512 * 2));
  unsigned short* kf  = (unsigned short*)(ws + alloc((size_t)16 * 1024 * 512 * 2));
  unsigned short* vf  = (unsigned short*)(ws + alloc((size_t)16 * 1024 * 2048 * 2));
  unsigned short* vfT = (unsigned short*)(ws + alloc((size_t)16 * 1024 * 2048 * 2));
  unsigned short* P   = vf;   // vf dead after transpose; P (32 MB) fits in vf (64 MB)

  prep_kernel<<<17, 256, 0, stream>>>(bq, aq, bk, ak, bv, av, Wp,
                                      ball, aall, Wps);

  qkv_mfma<<<dim3(512, 4), 256, 0, stream>>>(
      x, Wq, Wk, Wv, ball, aall, gq, gk, gv, beq, bek, bev, qf, kf, vf);

  transpose_v<<<dim3(32, 16, 16), 256, 0, stream>>>(vf, vfT);

  // S = scale * Q K^T   -> P (bf16, aliases dead vf)
  gemm_bt<<<dim3(8, 8, 16), 256, 0, stream>>>(
      qf, kf, P, (float*)nullptr, 1024, 1024, 512,
      (long)1024 * 512, (long)1024 * 512, (long)1024 * 1024,
      0.04419417382f /* 1/sqrt(512) */, 0);

  softmax_kernel<<<dim3(1024, 16), 256, 0, stream>>>(P);

  // attn_out = P @ V  -> fp32 scatter directly into d_out (b,c,t,f)
  gemm_bt<<<dim3(16, 8, 16), 256, 0, stream>>>(
      P, vfT, (unsigned short*)nullptr, out, 1024, 2048, 1024,
      (long)1024 * 1024, (long)2048 * 1024, 0, 1.0f, 1);

  // proj + norm + residual, in place on d_out
  proj_kernel<<<dim3(1024, 4), 256, 0, stream>>>(out, Wps, bp, ap, gp, bep, x);
}

// Round 3
// 522.236 us; speedup vs baseline: 1.2560x; 1.2560x over previous
//
#include <hip/hip_runtime.h>
#include <hip/hip_bf16.h>

typedef __attribute__((ext_vector_type(4))) float f32x4;
typedef __attribute__((ext_vector_type(8))) short short8;

__device__ __forceinline__ float bf2f(unsigned short u){
  union { unsigned u32; float f; } v; v.u32 = ((unsigned)u) << 16; return v.f;
}
__device__ __forceinline__ unsigned short f2bf(float f){
  union { float f; unsigned u; } v; v.f = f;
  unsigned x = v.u;
  unsigned r = x + 0x7fffu + ((x >> 16) & 1u);
  return (unsigned short)(r >> 16);
}
__device__ __forceinline__ short8 pack8(f32x4 a, f32x4 b){
  short8 r;
  r[0]=(short)f2bf(a[0]); r[1]=(short)f2bf(a[1]);
  r[2]=(short)f2bf(a[2]); r[3]=(short)f2bf(a[3]);
  r[4]=(short)f2bf(b[0]); r[5]=(short)f2bf(b[1]);
  r[6]=(short)f2bf(b[2]); r[7]=(short)f2bf(b[3]);
  return r;
}

// async global->LDS, 16B per lane. LDS dest is wave-uniform base + lane*16.
__device__ __forceinline__ void gload_lds16(const unsigned short* g, unsigned short* l) {
  __builtin_amdgcn_global_load_lds(
      (const __attribute__((address_space(1))) unsigned int*)g,
      (__attribute__((address_space(3))) unsigned int*)l, 16, 0, 0);
}

// ---------------------------------------------------------------------------
// K0: tiny prep — ball[96], aall[96] (row order: 0..15 q (h*4+o), 16..31 k,
// 32..95 v (h*16+o)), Wps[c][o] = Wp[o][c].
// ---------------------------------------------------------------------------
__global__ __launch_bounds__(256) void prep_kernel(
    const float* bq, const float* aq, const float* bk, const float* ak,
    const float* bv, const float* av, const float* Wp,
    float* ball, float* aall, float* Wps)
{
  int idx = blockIdx.x * 256 + threadIdx.x;
  if (idx < 96) {
    int j = idx;
    float b, a;
    if (j < 16)      { b = bq[j];      a = aq[j >> 2]; }
    else if (j < 32) { b = bk[j - 16]; a = ak[(j - 16) >> 2]; }
    else             { b = bv[j - 32]; a = av[(j - 32) >> 4]; }
    ball[j] = b; aall[j] = a;
  } else if (idx < 96 + 4096) {
    int r = idx - 96; int o = r >> 6, c = r & 63;
    Wps[c * 64 + o] = Wp[o * 64 + c];
  }
}

// ---------------------------------------------------------------------------
// K1: MFMA QKV. Occupancy is REGISTER-bound (~92 VGPR + 96 acc): do NOT
// force min-waves (launch_bounds(256,4) spilled acc -> 3x HBM traffic, R2).
// ---------------------------------------------------------------------------
__global__ __launch_bounds__(256, 2) void qkv_mfma(
    const float* __restrict__ x,
    const float* __restrict__ Wq, const float* __restrict__ Wk,
    const float* __restrict__ Wv,
    const float* __restrict__ ball, const float* __restrict__ aall,
    const float* __restrict__ gq, const float* __restrict__ gk,
    const float* __restrict__ gv,
    const float* __restrict__ beq, const float* __restrict__ bek,
    const float* __restrict__ bev,
    unsigned short* __restrict__ qf, unsigned short* __restrict__ kf,
    unsigned short* __restrict__ vf)
{
  __shared__ unsigned short upool[256 * 64];   // xl (32KB) then yl 48x264 (25.3KB)
  __shared__ float partS[4][96], partQ[4][96];
  __shared__ float gm[2][12], gi[2][12];
  __shared__ float bias_l[96], a_l[96];

  int tid = threadIdx.x;
  int t0 = blockIdx.x * 2, b = blockIdx.y;
  int lane = tid & 63, wave = tid >> 6;
  int l15 = lane & 15, quad = lane >> 4;

  if (tid < 96) { bias_l[tid] = ball[tid]; a_l[tid] = aall[tid]; }

  // ---- A fragments: W rows j = 16*mt + l15, k = 32*ks + quad*8 + [0..8) ----
  const float* wsrc[6] = {
    Wq + l15 * 64, Wk + l15 * 64,
    Wv + l15 * 64, Wv + (16 + l15) * 64,
    Wv + (32 + l15) * 64, Wv + (48 + l15) * 64
  };
  short8 afr[6][2];
  #pragma unroll
  for (int mt = 0; mt < 6; mt++)
    #pragma unroll
    for (int ks = 0; ks < 2; ks++) {
      const float* p = wsrc[mt] + ks * 32 + quad * 8;
      afr[mt][ks] = pack8(*(const f32x4*)p, *(const f32x4*)(p + 4));
    }

  // ---- stage X -> LDS (bf16, transposed to [n][c], swizzled) ----
  unsigned short* xl = upool;
  #pragma unroll
  for (int it = 0; it < 4; it++) {
    int item = it * 256 + tid;      // [0,1024): 8 cb x 128 np
    int cb = item >> 7;             // c-block 0..7
    int np = item & 127;            // n-pair
    int n = np * 2;
    int tl = n >> 7, f = n & 127;
    const float* gp = x + ((long)(b * 64 + cb * 8) * 1024 + t0 + tl) * 128 + f;
    short8 lo, hi;
    #pragma unroll
    for (int w = 0; w < 8; w++) {
      float2 v = *(const float2*)(gp + (long)w * 131072);
      lo[w] = (short)f2bf(v.x);
      hi[w] = (short)f2bf(v.y);
    }
    int perm = cb ^ (np & 7);       // key = (n>>1)&7, same for n and n+1
    *(short8*)&xl[n * 64 + perm * 8]       = lo;
    *(short8*)&xl[(n + 1) * 64 + perm * 8] = hi;
  }
  __syncthreads();

  // ---- MFMA: acc[mt][nt] = W-tile x X-tile ----
  f32x4 acc[6][4];
  #pragma unroll
  for (int mt = 0; mt < 6; mt++)
    #pragma unroll
    for (int nt = 0; nt < 4; nt++)
      acc[mt][nt] = {0.f, 0.f, 0.f, 0.f};

  int nb = wave * 64;
  #pragma unroll
  for (int ks = 0; ks < 2; ks++)
    #pragma unroll
    for (int nt = 0; nt < 4; nt++) {
      int n = nb + nt * 16 + l15;
      int perm = (ks * 4 + quad) ^ ((n >> 1) & 7);
      short8 bfrag = *(const short8*)&xl[n * 64 + perm * 8];
      #pragma unroll
      for (int mt = 0; mt < 6; mt++)
        acc[mt][nt] = __builtin_amdgcn_mfma_f32_16x16x32_bf16(
            afr[mt][ks], bfrag, acc[mt][nt], 0, 0, 0);
    }

  // ---- bias + PReLU, then per-row partial sums over this wave's 64 cols ----
  #pragma unroll
  for (int mt = 0; mt < 6; mt++)
    #pragma unroll
    for (int r = 0; r < 4; r++) {
      int j = mt * 16 + quad * 4 + r;
      float bb = bias_l[j], aa = a_l[j];
      #pragma unroll
      for (int nt = 0; nt < 4; nt++) {
        float v = acc[mt][nt][r] + bb;
        acc[mt][nt][r] = v > 0.f ? v : aa * v;
      }
      float s  = acc[mt][0][r] + acc[mt][1][r] + acc[mt][2][r] + acc[mt][3][r];
      float q2 = acc[mt][0][r]*acc[mt][0][r] + acc[mt][1][r]*acc[mt][1][r]
               + acc[mt][2][r]*acc[mt][2][r] + acc[mt][3][r]*acc[mt][3][r];
      #pragma unroll
      for (int m = 1; m <= 8; m <<= 1) {
        s  += __shfl_xor(s,  m, 64);
        q2 += __shfl_xor(q2, m, 64);
      }
      if (l15 == 0) { partS[wave][j] = s; partQ[wave][j] = q2; }
    }
  __syncthreads();   // xl reads done everywhere; partS/Q complete

  // ---- group stats (needs only partS/partQ) ----
  if (tid < 24) {
    int g = tid % 12, tl2 = tid / 12;
    int r0 = (g < 4) ? g * 4 : (g < 8) ? 16 + (g - 4) * 4 : 32 + (g - 8) * 16;
    int nr = (g < 8) ? 4 : 16;
    float S = 0.f, Q = 0.f;
    for (int w = tl2 * 2; w < tl2 * 2 + 2; w++)
      for (int r = 0; r < nr; r++) { S += partS[w][r0 + r]; Q += partQ[w][r0 + r]; }
    float cnt = (float)(nr * 128);
    float mean = S / cnt;
    float var = fmaxf(Q / cnt - mean * mean, 0.f);
    gm[tl2][g] = mean;
    gi[tl2][g] = rsqrtf(var + 1e-5f);
  }

  // ---- two-pass epilogue: stash 48 rows as bf16, normalize, store; repeat --
  unsigned short* yl = upool;   // 48 rows, pitch 264 (25.3KB; fits xl pool)
  int ch = tid & 31, jrow = tid >> 5;

  #pragma unroll
  for (int half = 0; half < 2; half++) {
    int jbase = half * 48;
    #pragma unroll
    for (int mt3 = 0; mt3 < 3; mt3++) {
      int mt = half * 3 + mt3;
      #pragma unroll
      for (int nt = 0; nt < 4; nt++) {
        int n = nb + nt * 16 + l15;
        #pragma unroll
        for (int r = 0; r < 4; r++) {
          int jrel = mt3 * 16 + quad * 4 + r;
          yl[jrel * 264 + n] = f2bf(acc[mt][nt][r]);
        }
      }
    }
    __syncthreads();   // yl half ready (and gm/gi ready on first pass)

    #pragma unroll
    for (int itj = 0; itj < 6; itj++) {
      int j = jbase + itj * 8 + jrow;
      int n0 = ch * 8;
      int tl3 = n0 >> 7, f = n0 & 127;
      short8 y8 = *(const short8*)&yl[(j - jbase) * 264 + n0];
      int g = (j < 16) ? (j >> 2) : (j < 32) ? 4 + ((j - 16) >> 2) : 8 + ((j - 32) >> 4);
      float mean = gm[tl3][g], inv = gi[tl3][g];
      const float *gsrc, *bsrc;
      int jo;
      unsigned short* dst;
      if (j < 16) {
        jo = j; gsrc = gq; bsrc = beq;
        int h = j >> 2, o = j & 3;
        dst = qf + (((long)(h * 4 + b) * 1024 + t0 + tl3) * 512 + o * 128 + f);
      } else if (j < 32) {
        jo = j - 16; gsrc = gk; bsrc = bek;
        int h = jo >> 2, o = jo & 3;
        dst = kf + (((long)(h * 4 + b) * 1024 + t0 + tl3) * 512 + o * 128 + f);
      } else {
        jo = j - 32; gsrc = gv; bsrc = bev;
        int h = jo >> 4, o = jo & 15;
        dst = vf + (((long)(h * 4 + b) * 1024 + t0 + tl3) * 2048 + o * 128 + f);
      }
      f32x4 g0 = *(const f32x4*)(gsrc + jo * 128 + f);
      f32x4 g1 = *(const f32x4*)(gsrc + jo * 128 + f + 4);
      f32x4 b0 = *(const f32x4*)(bsrc + jo * 128 + f);
      f32x4 b1 = *(const f32x4*)(bsrc + jo * 128 + f + 4);
      short8 o8;
      #pragma unroll
      for (int i = 0; i < 4; i++) {
        o8[i]     = (short)f2bf((bf2f((unsigned short)y8[i])     - mean) * inv * g0[i] + b0[i]);
        o8[i + 4] = (short)f2bf((bf2f((unsigned short)y8[i + 4]) - mean) * inv * g1[i] + b1[i]);
      }
      *(short8*)dst = o8;
    }
    if (half == 0) __syncthreads();   // yl reads done before overwriting
  }
}

// ---------------------------------------------------------------------------
// K2: transpose vf[n][t][dv] -> vfT[n][dv][t]  (64x64 tiles via LDS, bf16)
// ---------------------------------------------------------------------------
__global__ __launch_bounds__(256) void transpose_v(
    const unsigned short* __restrict__ vf, unsigned short* __restrict__ vfT)
{
  __shared__ unsigned short tile[64][65];
  int n = blockIdx.z;
  int d0 = blockIdx.x * 64, t0 = blockIdx.y * 64;
  int tid = threadIdx.x;
  int cr = tid >> 4, cc = (tid & 15) * 4;

  const unsigned short* src = vf + ((long)n * 1024 + t0) * 2048 + d0;
  #pragma unroll
  for (int i = 0; i < 4; i++) {
    int r = cr + i * 16;   // t-local
    ushort4 u = *(const ushort4*)(src + (long)r * 2048 + cc);
    tile[r][cc + 0] = u.x; tile[r][cc + 1] = u.y;
    tile[r][cc + 2] = u.z; tile[r][cc + 3] = u.w;
  }
  __syncthreads();
  unsigned short* dst = vfT + ((long)n * 2048 + d0) * 1024 + t0;
  #pragma unroll
  for (int i = 0; i < 4; i++) {
    int r = cr + i * 16;   // d-local
    ushort4 u;
    u.x = tile[cc + 0][r]; u.y = tile[cc + 1][r];
    u.z = tile[cc + 2][r]; u.w = tile[cc + 3][r];
    *(ushort4*)(dst + (long)r * 1024 + cc) = u;
  }
}

// ---------------------------------------------------------------------------
// K3: batched GEMM, D = scale * A B^T (both k-contiguous), bf16 in/out.
// 128x128 tile, BK=64 (half the barriers of BK=32), 4 waves, 32 MFMA/iter.
// global_load_lds dwordx4 into linear [128][64]-ushort LDS; slot swizzle key
// row&7 (8 slots/row): ds_read slot = (ks*4+quad)^(row&7) covers all 8
// 4-bank groups per 8-lane phase -> conflict-free. Source pre-swizzled with
// the same involution. Epilogue stages C in LDS (bf16, pitch 136) and stores
// linear short8 -> full 64B lines (no RMW). Output row-major bf16, batch z
// split across two base pointers: z<8 -> CbA + z*sC, else CbB + (z-8)*sC.
// XCD-aware bijective block swizzle (nwg%8==0).
// ---------------------------------------------------------------------------
__global__ __launch_bounds__(256) void gemm_bt(
    const unsigned short* __restrict__ A, const unsigned short* __restrict__ B,
    unsigned short* __restrict__ CbA, unsigned short* __restrict__ CbB,
    int M, int N, int K, long sA, long sB, long sC, float scale)
{
  __shared__ unsigned short smem[128 * 136];   // As[128*64] Bs[128*64]; C staging
  unsigned short* As = smem;
  unsigned short* Bs = smem + 128 * 64;
  int tid = threadIdx.x;

  // ---- XCD-aware bijective swizzle of the linearized block id ----
  int gx = gridDim.x, gy = gridDim.y;
  int bid = blockIdx.x + gx * (blockIdx.y + gy * blockIdx.z);
  int nwg = gx * gy * (int)gridDim.z;     // 1024 (QK) / 2048 (PV): % 8 == 0
  int cpx = nwg >> 3;
  int tile = (bid & 7) * cpx + (bid >> 3);
  int tx = tile % gx, trem = tile / gx;
  int ty = trem % gy, z = trem / gy;

  int m0 = ty * 128, n0 = tx * 128;
  const unsigned short* Ab = A + (long)z * sA + (long)m0 * K;
  const unsigned short* Bb = B + (long)z * sB + (long)n0 * K;
  int lane = tid & 63, wave = tid >> 6;
  int wm = (wave >> 1) * 64, wn = (wave & 1) * 64;
  int l15 = lane & 15, quad = lane >> 4;

  f32x4 acc[4][4];
  #pragma unroll
  for (int i = 0; i < 4; i++)
    #pragma unroll
    for (int j = 0; j < 4; j++) acc[i][j] = {0.f, 0.f, 0.f, 0.f};

  // staging: one gload call = 64 lanes x 16B = 8 rows of 128B.
  // lane -> row = R + (lane>>3), slot = lane&7; source chunk pre-swizzled.
  int srow8 = lane >> 3;
  int sck   = (lane & 7) ^ srow8;        // R%8==0 -> row&7 == lane>>3

  for (int k0 = 0; k0 < K; k0 += 64) {
    #pragma unroll
    for (int it = 0; it < 4; it++) {
      int R = it * 32 + wave * 8;        // 4 its x 4 waves x 8 rows = 128
      int row = R + srow8;
      gload_lds16(Ab + (long)row * K + k0 + sck * 8, &As[R * 64]);
      gload_lds16(Bb + (long)row * K + k0 + sck * 8, &Bs[R * 64]);
    }
    __syncthreads();                     // drains vmcnt before ds_read
    #pragma unroll
    for (int ks = 0; ks < 2; ks++) {
      short8 af[4], bfr[4];
      #pragma unroll
      for (int i = 0; i < 4; i++) {
        int row = wm + i * 16 + l15;
        af[i] = *(const short8*)&As[row * 64 + ((ks * 4 + quad) ^ (row & 7)) * 8];
      }
      #pragma unroll
      for (int j = 0; j < 4; j++) {
        int row = wn + j * 16 + l15;
        bfr[j] = *(const short8*)&Bs[row * 64 + ((ks * 4 + quad) ^ (row & 7)) * 8];
      }
      #pragma unroll
      for (int i = 0; i < 4; i++)
        #pragma unroll
        for (int j = 0; j < 4; j++)
          acc[i][j] = __builtin_amdgcn_mfma_f32_16x16x32_bf16(af[i], bfr[j], acc[i][j], 0, 0, 0);
    }
    __syncthreads();
  }

  // ---- epilogue: C tile -> LDS (bf16, pitch 136) -> full-line stores ----
  #pragma unroll
  for (int i = 0; i < 4; i++)
    #pragma unroll
    for (int j = 0; j < 4; j++) {
      int row0 = wm + i * 16 + quad * 4;
      int col = wn + j * 16 + l15;
      #pragma unroll
      for (int r = 0; r < 4; r++)
        smem[(row0 + r) * 136 + col] = f2bf(acc[i][j][r] * scale);
    }
  __syncthreads();
  unsigned short* Cz = (z < 8) ? (CbA + (long)z * sC) : (CbB + (long)(z - 8) * sC);
  #pragma unroll
  for (int it = 0; it < 8; it++) {
    int chunk = it * 256 + tid;          // 2048 chunks of 8 ushorts
    int row = chunk >> 4, c8 = (chunk & 15) * 8;
    *(short8*)(Cz + (long)(m0 + row) * N + n0 + c8) = *(const short8*)&smem[row * 136 + c8];
  }
}

// ---------------------------------------------------------------------------
// K4: in-place row softmax on P[z][row][0..1024) (bf16, already scaled)
// ---------------------------------------------------------------------------
__global__ __launch_bounds__(256) void softmax_kernel(unsigned short* __restrict__ P)
{
  __shared__ float red[4];
  __shared__ float bmax, bsum;
  int row = blockIdx.x, z = blockIdx.y, tid = threadIdx.x;
  unsigned short* p = P + ((long)z * 1024 + row) * 1024;
  ushort4 u = *(ushort4*)(p + tid * 4);
  float v0 = bf2f(u.x), v1 = bf2f(u.y), v2 = bf2f(u.z), v3 = bf2f(u.w);

  float m = fmaxf(fmaxf(v0, v1), fmaxf(v2, v3));
  #pragma unroll
  for (int s = 1; s <= 32; s <<= 1) m = fmaxf(m, __shfl_xor(m, s, 64));
  if ((tid & 63) == 0) red[tid >> 6] = m;
  __syncthreads();
  if (tid == 0) bmax = fmaxf(fmaxf(red[0], red[1]), fmaxf(red[2], red[3]));
  __syncthreads();
  m = bmax;

  float e0 = __expf(v0 - m), e1 = __expf(v1 - m), e2 = __expf(v2 - m), e3 = __expf(v3 - m);
  float s = e0 + e1 + e2 + e3;
  #pragma unroll
  for (int k = 1; k <= 32; k <<= 1) s += __shfl_xor(s, k, 64);
  if ((tid & 63) == 0) red[tid >> 6] = s;
  __syncthreads();
  if (tid == 0) bsum = red[0] + red[1] + red[2] + red[3];
  __syncthreads();
  float inv = 1.0f / bsum;

  u.x = f2bf(e0 * inv); u.y = f2bf(e1 * inv);
  u.z = f2bf(e2 * inv); u.w = f2bf(e3 * inv);
  *(ushort4*)(p + tid * 4) = u;
}

// ---------------------------------------------------------------------------
// K5: proj (64x64) + bias + PReLU + ChannelNorm over (C,F) + gp/betap + x.
// Reads attn_out from bf16 of[z][t][dv] (z = h*4+b, split base pointers),
// writes fp32 d_out (b,c,t,f).
// ---------------------------------------------------------------------------
__global__ __launch_bounds__(256) void proj_kernel(
    float* __restrict__ io,
    const unsigned short* __restrict__ ofA, const unsigned short* __restrict__ ofB,
    const float* __restrict__ Wps,
    const float* __restrict__ bp, const float* __restrict__ ap,
    const float* __restrict__ gp, const float* __restrict__ bep,
    const float* __restrict__ x)
{
  __shared__ float xl[64 * 128];
  __shared__ float wl[64 * 64];
  __shared__ float redS[4], redQ[4];
  __shared__ float smean, sinv;

  int tid = threadIdx.x;
  int t = blockIdx.x, b = blockIdx.y;

  // stage attn_out (b, :, t, :) from of: 4 h-slices x 4KB contiguous bf16
  #pragma unroll
  for (int i = 0; i < 4; i++) {
    int chunk = i * 256 + tid;           // 1024 chunks of 8
    int h = chunk >> 8;
    int dvc = (chunk & 255) * 8;
    int z = h * 4 + b;
    const unsigned short* base =
        (z < 8) ? (ofA + (long)z * 2097152) : (ofB + (long)(z - 8) * 2097152);
    short8 v = *(const short8*)(base + (long)t * 2048 + dvc);
    int c = h * 16 + (dvc >> 7);
    int f = dvc & 127;
    #pragma unroll
    for (int e = 0; e < 8; e++) xl[c * 128 + f + e] = bf2f((unsigned short)v[e]);
  }
  #pragma unroll
  for (int i = 0; i < 4; i++) {
    int id = tid + i * 256;
    ((f32x4*)wl)[id] = ((const f32x4*)Wps)[id];
  }
  __syncthreads();

  int fblk = tid & 31, rblk = tid >> 5;
  int f0 = fblk * 4, r0 = rblk * 8;

  float acc[8][4];
  #pragma unroll
  for (int rr = 0; rr < 8; rr++)
    #pragma unroll
    for (int ff = 0; ff < 4; ff++) acc[rr][ff] = 0.f;

  for (int c = 0; c < 64; c++) {
    f32x4 xv = *(const f32x4*)&xl[c * 128 + f0];
    f32x4 w0 = *(const f32x4*)&wl[c * 64 + r0];
    f32x4 w1 = *(const f32x4*)&wl[c * 64 + r0 + 4];
    #pragma unroll
    for (int rr = 0; rr < 4; rr++) {
      #pragma unroll
      for (int ff = 0; ff < 4; ff++) {
        acc[rr][ff]     += w0[rr] * xv[ff];
        acc[rr + 4][ff] += w1[rr] * xv[ff];
      }
    }
  }

  float aval = ap[0];
  #pragma unroll
  for (int rr = 0; rr < 8; rr++) {
    float bb = bp[r0 + rr];
    #pragma unroll
    for (int ff = 0; ff < 4; ff++) {
      float v = acc[rr][ff] + bb;
      acc[rr][ff] = v > 0.f ? v : aval * v;
    }
  }

  float s = 0.f, sq = 0.f;
  #pragma unroll
  for (int rr = 0; rr < 8; rr++)
    #pragma unroll
    for (int ff = 0; ff < 4; ff++) { s += acc[rr][ff]; sq += acc[rr][ff] * acc[rr][ff]; }
  #pragma unroll
  for (int m = 1; m <= 32; m <<= 1) { s += __shfl_xor(s, m, 64); sq += __shfl_xor(sq, m, 64); }
  if ((tid & 63) == 0) { redS[tid >> 6] = s; redQ[tid >> 6] = sq; }
  __syncthreads();
  if (tid == 0) {
    float S = redS[0] + redS[1] + redS[2] + redS[3];
    float Q = redQ[0] + redQ[1] + redQ[2] + redQ[3];
    float mean = S / 8192.0f;
    float var = fmaxf(Q / 8192.0f - mean * mean, 0.f);
    smean = mean; sinv = rsqrtf(var + 1e-5f);
  }
  __syncthreads();
  float mean = smean, inv = sinv;

  const float* xb = x + ((long)(b * 64) * 1024 + t) * 128;
  #pragma unroll
  for (int rr = 0; rr < 8; rr++) {
    int c = r0 + rr;
    f32x4 g4 = *(const f32x4*)(gp + c * 128 + f0);
    f32x4 b4 = *(const f32x4*)(bep + c * 128 + f0);
    f32x4 x4 = *(const f32x4*)(xb + (long)c * 131072 + f0);
    f32x4 o;
    o[0] = (acc[rr][0] - mean) * inv * g4[0] + b4[0] + x4[0];
    o[1] = (acc[rr][1] - mean) * inv * g4[1] + b4[1] + x4[1];
    o[2] = (acc[rr][2] - mean) * inv * g4[2] + b4[2] + x4[2];
    o[3] = (acc[rr][3] - mean) * inv * g4[3] + b4[3] + x4[3];
    *(f32x4*)(io + ((long)(b * 64 + c) * 1024 + t) * 128 + f0) = o;
  }
}

// ---------------------------------------------------------------------------
extern "C" void kernel_launch(void* const* d_in, const int* in_sizes, int n_in,
                              void* d_out, int out_size, void* d_ws, size_t ws_size,
                              hipStream_t stream)
{
  const float* x   = (const float*)d_in[0];
  const float* Wq  = (const float*)d_in[1];
  const float* bq  = (const float*)d_in[2];
  const float* aq  = (const float*)d_in[3];
  const float* gq  = (const float*)d_in[4];
  const float* beq = (const float*)d_in[5];
  const float* Wk  = (const float*)d_in[6];
  const float* bk  = (const float*)d_in[7];
  const float* ak  = (const float*)d_in[8];
  const float* gk  = (const float*)d_in[9];
  const float* bek = (const float*)d_in[10];
  const float* Wv  = (const float*)d_in[11];
  const float* bv  = (const float*)d_in[12];
  const float* av  = (const float*)d_in[13];
  const float* gv  = (const float*)d_in[14];
  const float* bev = (const float*)d_in[15];
  const float* Wp  = (const float*)d_in[16];
  const float* bp  = (const float*)d_in[17];
  const float* ap  = (const float*)d_in[18];
  const float* gp  = (const float*)d_in[19];
  const float* bep = (const float*)d_in[20];
  float* out = (float*)d_out;

  char* ws = (char*)d_ws;
  size_t off = 0;
  auto alloc = [&](size_t n) { size_t o = off; off += (n + 255) & ~(size_t)255; return o; };

  float* ball = (float*)(ws + alloc(96 * 4));
  float* aall = (float*)(ws + alloc(96 * 4));
  float* Wps  = (float*)(ws + alloc(4096 * 4));
  unsigned short* qf  = (unsigned short*)(ws + alloc((size_t)16 * 1024 * 512 * 2));
  unsigned short* kf  = (unsigned short*)(ws + alloc((size_t)16 * 1024 * 512 * 2));
  unsigned short* vf  = (unsigned short*)(ws + alloc((size_t)16 * 1024 * 2048 * 2));
  unsigned short* vfT = (unsigned short*)(ws + alloc((size_t)16 * 1024 * 2048 * 2));
  unsigned short* P   = vf;   // vf dead after transpose; P (32 MB) in vf lower half
  // attn_out bf16 of[z][1024][2048]: z<8 in dead qf+kf (32 MB contiguous),
  // z>=8 in vf upper half (32 MB, disjoint from P).
  unsigned short* ofA = qf;
  unsigned short* ofB = (unsigned short*)((char*)vf + (size_t)32 * 1024 * 1024);

  prep_kernel<<<17, 256, 0, stream>>>(bq, aq, bk, ak, bv, av, Wp,
                                      ball, aall, Wps);

  qkv_mfma<<<dim3(512, 4), 256, 0, stream>>>(
      x, Wq, Wk, Wv, ball, aall, gq, gk, gv, beq, bek, bev, qf, kf, vf);

  transpose_v<<<dim3(32, 16, 16), 256, 0, stream>>>(vf, vfT);

  // S = scale * Q K^T -> P (bf16)
  gemm_bt<<<dim3(8, 8, 16), 256, 0, stream>>>(
      qf, kf, P, P + (long)8 * 1024 * 1024, 1024, 1024, 512,
      (long)1024 * 512, (long)1024 * 512, (long)1024 * 1024,
      0.04419417382f /* 1/sqrt(512) */);

  softmax_kernel<<<dim3(1024, 16), 256, 0, stream>>>(P);

  // attn_out = P @ V -> bf16 row-major of[z][t][dv]
  gemm_bt<<<dim3(16, 8, 16), 256, 0, stream>>>(
      P, vfT, ofA, ofB, 1024, 2048, 1024,
      (long)1024 * 1024, (long)2048 * 1024, (long)1024 * 2048, 1.0f);

  // proj + norm + residual
  proj_kernel<<<dim3(1024, 4), 256, 0, stream>>>(out, ofA, ofB, Wps, bp, ap, gp, bep, x);
}

// Round 4
// 517.877 us; speedup vs baseline: 1.2665x; 1.0084x over previous
//
#include <hip/hip_runtime.h>
#include <hip/hip_bf16.h>

typedef __attribute__((ext_vector_type(4))) float f32x4;
typedef __attribute__((ext_vector_type(8))) short short8;

__device__ __forceinline__ float bf2f(unsigned short u){
  union { unsigned u32; float f; } v; v.u32 = ((unsigned)u) << 16; return v.f;
}
__device__ __forceinline__ unsigned short f2bf(float f){
  union { float f; unsigned u; } v; v.f = f;
  unsigned x = v.u;
  unsigned r = x + 0x7fffu + ((x >> 16) & 1u);
  return (unsigned short)(r >> 16);
}

// async global->LDS, 16B per lane. LDS dest is wave-uniform base + lane*16.
__device__ __forceinline__ void gload_lds16(const unsigned short* g, unsigned short* l) {
  __builtin_amdgcn_global_load_lds(
      (const __attribute__((address_space(1))) unsigned int*)g,
      (__attribute__((address_space(3))) unsigned int*)l, 16, 0, 0);
}

// ---------------------------------------------------------------------------
// K0: prep — ball[96], aall[96] (row order: 0..15 q (h*4+o), 16..31 k,
// 32..95 v (h*16+o)); Wps[c][o] = Wp[o][c]; bf16 Wbf[96][64];
// bf16 gba/bba[96][128] (gamma/beta in the same row order).
// ---------------------------------------------------------------------------
__global__ __launch_bounds__(256) void prep_kernel(
    const float* bq, const float* aq, const float* bk, const float* ak,
    const float* bv, const float* av, const float* Wp,
    const float* Wq, const float* Wk, const float* Wv,
    const float* gq, const float* gk, const float* gv,
    const float* beq, const float* bek, const float* bev,
    float* ball, float* aall, float* Wps,
    unsigned short* Wbf, unsigned short* gba, unsigned short* bba)
{
  int idx = blockIdx.x * 256 + threadIdx.x;
  if (idx < 96) {
    int j = idx;
    float b, a;
    if (j < 16)      { b = bq[j];      a = aq[j >> 2]; }
    else if (j < 32) { b = bk[j - 16]; a = ak[(j - 16) >> 2]; }
    else             { b = bv[j - 32]; a = av[(j - 32) >> 4]; }
    ball[j] = b; aall[j] = a;
  } else if (idx < 4192) {
    int r = idx - 96; int o = r >> 6, c = r & 63;
    Wps[c * 64 + o] = Wp[o * 64 + c];
  } else if (idx < 10336) {
    int r = idx - 4192; int j = r >> 6, c = r & 63;
    float w = (j < 16) ? Wq[j * 64 + c] : (j < 32) ? Wk[(j - 16) * 64 + c]
                                                   : Wv[(j - 32) * 64 + c];
    Wbf[j * 64 + c] = f2bf(w);
  } else if (idx < 22624) {
    int r = idx - 10336; int j = r >> 7, f = r & 127;
    float g = (j < 16) ? gq[j * 128 + f] : (j < 32) ? gk[(j - 16) * 128 + f]
                                                    : gv[(j - 32) * 128 + f];
    gba[j * 128 + f] = f2bf(g);
  } else if (idx < 34912) {
    int r = idx - 22624; int j = r >> 7, f = r & 127;
    float be = (j < 16) ? beq[j * 128 + f] : (j < 32) ? bek[(j - 16) * 128 + f]
                                                      : bev[(j - 32) * 128 + f];
    bba[j * 128 + f] = f2bf(be);
  }
}

// ---------------------------------------------------------------------------
// K1: MFMA QKV, one t per block (grid 1024 x 4). 4 waves as 2 row-groups x
// 2 col-groups: each wave 48 rows x 64 cols -> acc[3][4] (48 regs) +
// afr[3][2] (24 regs). Occupancy is register-bound; this halves the old
// per-wave acc footprint (was acc[6][4]+afr[6][2] ~144 -> 2 waves/SIMD).
// W/gamma/beta read as precomputed bf16 (no per-block conversions).
// LDS X layout: xl[f][c] pitch 64, c-blocks of 8 XOR-swizzled by (f>>1)&7.
// ---------------------------------------------------------------------------
__global__ __launch_bounds__(256, 3) void qkv_mfma(
    const float* __restrict__ x,
    const unsigned short* __restrict__ Wbf,
    const float* __restrict__ ball, const float* __restrict__ aall,
    const unsigned short* __restrict__ gba, const unsigned short* __restrict__ bba,
    unsigned short* __restrict__ qf, unsigned short* __restrict__ kf,
    unsigned short* __restrict__ vf)
{
  __shared__ unsigned short upool[128 * 64];   // xl 16KB; reused as yl 48x136
  __shared__ float partS[4][96], partQ[4][96];
  __shared__ float gm[12], gi[12];
  __shared__ float bias_l[96], a_l[96];

  int tid = threadIdx.x;
  int t = blockIdx.x, b = blockIdx.y;
  int lane = tid & 63, wave = tid >> 6;
  int l15 = lane & 15, quad = lane >> 4;
  int rowg = wave >> 1, colg = wave & 1;

  if (tid < 96) { bias_l[tid] = ball[tid]; a_l[tid] = aall[tid]; }

  // ---- A fragments from bf16 W (L2-hot): rows of this wave's row-group ----
  short8 afr[3][2];
  #pragma unroll
  for (int mt3 = 0; mt3 < 3; mt3++) {
    int row = (rowg * 3 + mt3) * 16 + l15;
    #pragma unroll
    for (int ks = 0; ks < 2; ks++)
      afr[mt3][ks] = *(const short8*)(Wbf + row * 64 + ks * 32 + quad * 8);
  }

  // ---- stage X(b,:,t,:) -> xl[f][c] bf16, swizzled ----
  unsigned short* xl = upool;
  #pragma unroll
  for (int it = 0; it < 2; it++) {
    int item = it * 256 + tid;      // 512 items: 8 cb x 64 f-pairs
    int cb = item >> 6;             // c-block 0..7
    int np = item & 63;             // f-pair
    int n = np * 2;
    const float* gp = x + ((long)(b * 64 + cb * 8) * 1024 + t) * 128 + n;
    short8 lo, hi;
    #pragma unroll
    for (int w = 0; w < 8; w++) {
      float2 v = *(const float2*)(gp + (long)w * 131072);
      lo[w] = (short)f2bf(v.x);
      hi[w] = (short)f2bf(v.y);
    }
    int perm = cb ^ (np & 7);       // key = (n>>1)&7, same for n and n+1
    *(short8*)&xl[n * 64 + perm * 8]       = lo;
    *(short8*)&xl[(n + 1) * 64 + perm * 8] = hi;
  }
  __syncthreads();

  // ---- MFMA: acc[mt3][nt] over this wave's 48 rows x 64 cols ----
  f32x4 acc[3][4];
  #pragma unroll
  for (int mt3 = 0; mt3 < 3; mt3++)
    #pragma unroll
    for (int nt = 0; nt < 4; nt++)
      acc[mt3][nt] = {0.f, 0.f, 0.f, 0.f};

  int nb = colg * 64;
  #pragma unroll
  for (int ks = 0; ks < 2; ks++)
    #pragma unroll
    for (int nt = 0; nt < 4; nt++) {
      int n = nb + nt * 16 + l15;
      int perm = (ks * 4 + quad) ^ ((n >> 1) & 7);
      short8 bfrag = *(const short8*)&xl[n * 64 + perm * 8];
      #pragma unroll
      for (int mt3 = 0; mt3 < 3; mt3++)
        acc[mt3][nt] = __builtin_amdgcn_mfma_f32_16x16x32_bf16(
            afr[mt3][ks], bfrag, acc[mt3][nt], 0, 0, 0);
    }

  // ---- bias + PReLU, per-row partial sums over this wave's 64 cols ----
  #pragma unroll
  for (int mt3 = 0; mt3 < 3; mt3++)
    #pragma unroll
    for (int r = 0; r < 4; r++) {
      int j = (rowg * 3 + mt3) * 16 + quad * 4 + r;
      float bb = bias_l[j], aa = a_l[j];
      #pragma unroll
      for (int nt = 0; nt < 4; nt++) {
        float v = acc[mt3][nt][r] + bb;
        acc[mt3][nt][r] = v > 0.f ? v : aa * v;
      }
      float s  = acc[mt3][0][r] + acc[mt3][1][r] + acc[mt3][2][r] + acc[mt3][3][r];
      float q2 = acc[mt3][0][r]*acc[mt3][0][r] + acc[mt3][1][r]*acc[mt3][1][r]
               + acc[mt3][2][r]*acc[mt3][2][r] + acc[mt3][3][r]*acc[mt3][3][r];
      #pragma unroll
      for (int m = 1; m <= 8; m <<= 1) {
        s  += __shfl_xor(s,  m, 64);
        q2 += __shfl_xor(q2, m, 64);
      }
      if (l15 == 0) { partS[wave][j] = s; partQ[wave][j] = q2; }
    }
  __syncthreads();   // xl reads done everywhere; partS/Q complete

  // ---- group stats: group g sums its rows over the 2 col-waves ----
  if (tid < 12) {
    int g = tid;
    int r0 = (g < 4) ? g * 4 : (g < 8) ? 16 + (g - 4) * 4 : 32 + (g - 8) * 16;
    int nr = (g < 8) ? 4 : 16;
    int rw = (r0 < 48) ? 0 : 2;         // wave base of the owning row-group
    float S = 0.f, Q = 0.f;
    for (int w2 = 0; w2 < 2; w2++)
      for (int r = 0; r < nr; r++) { S += partS[rw + w2][r0 + r]; Q += partQ[rw + w2][r0 + r]; }
    float cnt = (float)(nr * 128);
    float mean = S / cnt;
    float var = fmaxf(Q / cnt - mean * mean, 0.f);
    gm[g] = mean;
    gi[g] = rsqrtf(var + 1e-5f);
  }

  // ---- two-pass epilogue: row-half h stashed by row-group h, then all
  //      threads normalize + store that half with full-line bf16 stores ----
  unsigned short* yl = upool;   // 48 rows, pitch 136 (13KB; fits xl pool)
  int ch = tid & 15, jrow = tid >> 4;

  #pragma unroll
  for (int half = 0; half < 2; half++) {
    if (rowg == half) {
      #pragma unroll
      for (int mt3 = 0; mt3 < 3; mt3++)
        #pragma unroll
        for (int nt = 0; nt < 4; nt++) {
          int n = nb + nt * 16 + l15;
          #pragma unroll
          for (int r = 0; r < 4; r++) {
            int jrel = mt3 * 16 + quad * 4 + r;
            yl[jrel * 136 + n] = f2bf(acc[mt3][nt][r]);
          }
        }
    }
    __syncthreads();   // yl half ready (and gm/gi ready on first pass)

    #pragma unroll
    for (int itj = 0; itj < 3; itj++) {
      int jrel = itj * 16 + jrow;
      int j = half * 48 + jrel;
      int f = ch * 8;
      short8 y8 = *(const short8*)&yl[jrel * 136 + f];
      int g = (j < 16) ? (j >> 2) : (j < 32) ? 4 + ((j - 16) >> 2) : 8 + ((j - 32) >> 4);
      float mean = gm[g], inv = gi[g];
      unsigned short* dst;
      if (j < 16) {
        int h = j >> 2, o = j & 3;
        dst = qf + (((long)(h * 4 + b) * 1024 + t) * 512 + o * 128 + f);
      } else if (j < 32) {
        int jo = j - 16; int h = jo >> 2, o = jo & 3;
        dst = kf + (((long)(h * 4 + b) * 1024 + t) * 512 + o * 128 + f);
      } else {
        int jo = j - 32; int h = jo >> 4, o = jo & 15;
        dst = vf + (((long)(h * 4 + b) * 1024 + t) * 2048 + o * 128 + f);
      }
      short8 g8 = *(const short8*)(gba + j * 128 + f);
      short8 b8 = *(const short8*)(bba + j * 128 + f);
      short8 o8;
      #pragma unroll
      for (int i = 0; i < 8; i++)
        o8[i] = (short)f2bf((bf2f((unsigned short)y8[i]) - mean) * inv
                            * bf2f((unsigned short)g8[i]) + bf2f((unsigned short)b8[i]));
      *(short8*)dst = o8;
    }
    if (half == 0) __syncthreads();   // yl reads done before overwriting
  }
}

// ---------------------------------------------------------------------------
// K2: transpose vf[n][t][dv] -> vfT[n][dv][t]  (64x64 tiles via LDS, bf16)
// ---------------------------------------------------------------------------
__global__ __launch_bounds__(256) void transpose_v(
    const unsigned short* __restrict__ vf, unsigned short* __restrict__ vfT)
{
  __shared__ unsigned short tile[64][65];
  int n = blockIdx.z;
  int d0 = blockIdx.x * 64, t0 = blockIdx.y * 64;
  int tid = threadIdx.x;
  int cr = tid >> 4, cc = (tid & 15) * 4;

  const unsigned short* src = vf + ((long)n * 1024 + t0) * 2048 + d0;
  #pragma unroll
  for (int i = 0; i < 4; i++) {
    int r = cr + i * 16;   // t-local
    ushort4 u = *(const ushort4*)(src + (long)r * 2048 + cc);
    tile[r][cc + 0] = u.x; tile[r][cc + 1] = u.y;
    tile[r][cc + 2] = u.z; tile[r][cc + 3] = u.w;
  }
  __syncthreads();
  unsigned short* dst = vfT + ((long)n * 2048 + d0) * 1024 + t0;
  #pragma unroll
  for (int i = 0; i < 4; i++) {
    int r = cr + i * 16;   // d-local
    ushort4 u;
    u.x = tile[cc + 0][r]; u.y = tile[cc + 1][r];
    u.z = tile[cc + 2][r]; u.w = tile[cc + 3][r];
    *(ushort4*)(dst + (long)r * 1024 + cc) = u;
  }
}

// ---------------------------------------------------------------------------
// K3: batched GEMM, D = scale * A B^T (both k-contiguous), bf16 in/out.
// 128x128 tile, BK=64, 4 waves, 32 MFMA/iter. global_load_lds dwordx4 into
// linear [128][64]-ushort LDS; slot swizzle key row&7; source pre-swizzled.
// Epilogue stages C in LDS and stores full 64B lines. Output bf16 row-major,
// batch z split across two base pointers. XCD-aware bijective block swizzle.
// ---------------------------------------------------------------------------
__global__ __launch_bounds__(256) void gemm_bt(
    const unsigned short* __restrict__ A, const unsigned short* __restrict__ B,
    unsigned short* __restrict__ CbA, unsigned short* __restrict__ CbB,
    int M, int N, int K, long sA, long sB, long sC, float scale)
{
  __shared__ unsigned short smem[128 * 136];   // As[128*64] Bs[128*64]; C staging
  unsigned short* As = smem;
  unsigned short* Bs = smem + 128 * 64;
  int tid = threadIdx.x;

  // ---- XCD-aware bijective swizzle of the linearized block id ----
  int gx = gridDim.x, gy = gridDim.y;
  int bid = blockIdx.x + gx * (blockIdx.y + gy * blockIdx.z);
  int nwg = gx * gy * (int)gridDim.z;     // 1024 (QK) / 2048 (PV): % 8 == 0
  int cpx = nwg >> 3;
  int tile = (bid & 7) * cpx + (bid >> 3);
  int tx = tile % gx, trem = tile / gx;
  int ty = trem % gy, z = trem / gy;

  int m0 = ty * 128, n0 = tx * 128;
  const unsigned short* Ab = A + (long)z * sA + (long)m0 * K;
  const unsigned short* Bb = B + (long)z * sB + (long)n0 * K;
  int lane = tid & 63, wave = tid >> 6;
  int wm = (wave >> 1) * 64, wn = (wave & 1) * 64;
  int l15 = lane & 15, quad = lane >> 4;

  f32x4 acc[4][4];
  #pragma unroll
  for (int i = 0; i < 4; i++)
    #pragma unroll
    for (int j = 0; j < 4; j++) acc[i][j] = {0.f, 0.f, 0.f, 0.f};

  // staging: one gload call = 64 lanes x 16B = 8 rows of 128B.
  int srow8 = lane >> 3;
  int sck   = (lane & 7) ^ srow8;        // R%8==0 -> row&7 == lane>>3

  for (int k0 = 0; k0 < K; k0 += 64) {
    #pragma unroll
    for (int it = 0; it < 4; it++) {
      int R = it * 32 + wave * 8;        // 4 its x 4 waves x 8 rows = 128
      int row = R + srow8;
      gload_lds16(Ab + (long)row * K + k0 + sck * 8, &As[R * 64]);
      gload_lds16(Bb + (long)row * K + k0 + sck * 8, &Bs[R * 64]);
    }
    __syncthreads();                     // drains vmcnt before ds_read
    #pragma unroll
    for (int ks = 0; ks < 2; ks++) {
      short8 af[4], bfr[4];
      #pragma unroll
      for (int i = 0; i < 4; i++) {
        int row = wm + i * 16 + l15;
        af[i] = *(const short8*)&As[row * 64 + ((ks * 4 + quad) ^ (row & 7)) * 8];
      }
      #pragma unroll
      for (int j = 0; j < 4; j++) {
        int row = wn + j * 16 + l15;
        bfr[j] = *(const short8*)&Bs[row * 64 + ((ks * 4 + quad) ^ (row & 7)) * 8];
      }
      #pragma unroll
      for (int i = 0; i < 4; i++)
        #pragma unroll
        for (int j = 0; j < 4; j++)
          acc[i][j] = __builtin_amdgcn_mfma_f32_16x16x32_bf16(af[i], bfr[j], acc[i][j], 0, 0, 0);
    }
    __syncthreads();
  }

  // ---- epilogue: C tile -> LDS (bf16, pitch 136) -> full-line stores ----
  #pragma unroll
  for (int i = 0; i < 4; i++)
    #pragma unroll
    for (int j = 0; j < 4; j++) {
      int row0 = wm + i * 16 + quad * 4;
      int col = wn + j * 16 + l15;
      #pragma unroll
      for (int r = 0; r < 4; r++)
        smem[(row0 + r) * 136 + col] = f2bf(acc[i][j][r] * scale);
    }
  __syncthreads();
  unsigned short* Cz = (z < 8) ? (CbA + (long)z * sC) : (CbB + (long)(z - 8) * sC);
  #pragma unroll
  for (int it = 0; it < 8; it++) {
    int chunk = it * 256 + tid;          // 2048 chunks of 8 ushorts
    int row = chunk >> 4, c8 = (chunk & 15) * 8;
    *(short8*)(Cz + (long)(m0 + row) * N + n0 + c8) = *(const short8*)&smem[row * 136 + c8];
  }
}

// ---------------------------------------------------------------------------
// K4: in-place row softmax on P[z][row][0..1024) (bf16, already scaled)
// ---------------------------------------------------------------------------
__global__ __launch_bounds__(256) void softmax_kernel(unsigned short* __restrict__ P)
{
  __shared__ float red[4];
  __shared__ float bmax, bsum;
  int row = blockIdx.x, z = blockIdx.y, tid = threadIdx.x;
  unsigned short* p = P + ((long)z * 1024 + row) * 1024;
  ushort4 u = *(ushort4*)(p + tid * 4);
  float v0 = bf2f(u.x), v1 = bf2f(u.y), v2 = bf2f(u.z), v3 = bf2f(u.w);

  float m = fmaxf(fmaxf(v0, v1), fmaxf(v2, v3));
  #pragma unroll
  for (int s = 1; s <= 32; s <<= 1) m = fmaxf(m, __shfl_xor(m, s, 64));
  if ((tid & 63) == 0) red[tid >> 6] = m;
  __syncthreads();
  if (tid == 0) bmax = fmaxf(fmaxf(red[0], red[1]), fmaxf(red[2], red[3]));
  __syncthreads();
  m = bmax;

  float e0 = __expf(v0 - m), e1 = __expf(v1 - m), e2 = __expf(v2 - m), e3 = __expf(v3 - m);
  float s = e0 + e1 + e2 + e3;
  #pragma unroll
  for (int k = 1; k <= 32; k <<= 1) s += __shfl_xor(s, k, 64);
  if ((tid & 63) == 0) red[tid >> 6] = s;
  __syncthreads();
  if (tid == 0) bsum = red[0] + red[1] + red[2] + red[3];
  __syncthreads();
  float inv = 1.0f / bsum;

  u.x = f2bf(e0 * inv); u.y = f2bf(e1 * inv);
  u.z = f2bf(e2 * inv); u.w = f2bf(e3 * inv);
  *(ushort4*)(p + tid * 4) = u;
}

// ---------------------------------------------------------------------------
// K5: proj (64x64) + bias + PReLU + ChannelNorm over (C,F) + gp/betap + x.
// Reads attn_out from bf16 of[z][t][dv] (z = h*4+b, split base pointers),
// writes fp32 d_out (b,c,t,f).
// ---------------------------------------------------------------------------
__global__ __launch_bounds__(256) void proj_kernel(
    float* __restrict__ io,
    const unsigned short* __restrict__ ofA, const unsigned short* __restrict__ ofB,
    const float* __restrict__ Wps,
    const float* __restrict__ bp, const float* __restrict__ ap,
    const float* __restrict__ gp, const float* __restrict__ bep,
    const float* __restrict__ x)
{
  __shared__ float xl[64 * 128];
  __shared__ float wl[64 * 64];
  __shared__ float redS[4], redQ[4];
  __shared__ float smean, sinv;

  int tid = threadIdx.x;
  int t = blockIdx.x, b = blockIdx.y;

  // stage attn_out (b, :, t, :) from of: 4 h-slices x 4KB contiguous bf16
  #pragma unroll
  for (int i = 0; i < 4; i++) {
    int chunk = i * 256 + tid;           // 1024 chunks of 8
    int h = chunk >> 8;
    int dvc = (chunk & 255) * 8;
    int z = h * 4 + b;
    const unsigned short* base =
        (z < 8) ? (ofA + (long)z * 2097152) : (ofB + (long)(z - 8) * 2097152);
    short8 v = *(const short8*)(base + (long)t * 2048 + dvc);
    int c = h * 16 + (dvc >> 7);
    int f = dvc & 127;
    #pragma unroll
    for (int e = 0; e < 8; e++) xl[c * 128 + f + e] = bf2f((unsigned short)v[e]);
  }
  #pragma unroll
  for (int i = 0; i < 4; i++) {
    int id = tid + i * 256;
    ((f32x4*)wl)[id] = ((const f32x4*)Wps)[id];
  }
  __syncthreads();

  int fblk = tid & 31, rblk = tid >> 5;
  int f0 = fblk * 4, r0 = rblk * 8;

  float acc[8][4];
  #pragma unroll
  for (int rr = 0; rr < 8; rr++)
    #pragma unroll
    for (int ff = 0; ff < 4; ff++) acc[rr][ff] = 0.f;

  for (int c = 0; c < 64; c++) {
    f32x4 xv = *(const f32x4*)&xl[c * 128 + f0];
    f32x4 w0 = *(const f32x4*)&wl[c * 64 + r0];
    f32x4 w1 = *(const f32x4*)&wl[c * 64 + r0 + 4];
    #pragma unroll
    for (int rr = 0; rr < 4; rr++) {
      #pragma unroll
      for (int ff = 0; ff < 4; ff++) {
        acc[rr][ff]     += w0[rr] * xv[ff];
        acc[rr + 4][ff] += w1[rr] * xv[ff];
      }
    }
  }

  float aval = ap[0];
  #pragma unroll
  for (int rr = 0; rr < 8; rr++) {
    float bb = bp[r0 + rr];
    #pragma unroll
    for (int ff = 0; ff < 4; ff++) {
      float v = acc[rr][ff] + bb;
      acc[rr][ff] = v > 0.f ? v : aval * v;
    }
  }

  float s = 0.f, sq = 0.f;
  #pragma unroll
  for (int rr = 0; rr < 8; rr++)
    #pragma unroll
    for (int ff = 0; ff < 4; ff++) { s += acc[rr][ff]; sq += acc[rr][ff] * acc[rr][ff]; }
  #pragma unroll
  for (int m = 1; m <= 32; m <<= 1) { s += __shfl_xor(s, m, 64); sq += __shfl_xor(sq, m, 64); }
  if ((tid & 63) == 0) { redS[tid >> 6] = s; redQ[tid >> 6] = sq; }
  __syncthreads();
  if (tid == 0) {
    float S = redS[0] + redS[1] + redS[2] + redS[3];
    float Q = redQ[0] + redQ[1] + redQ[2] + redQ[3];
    float mean = S / 8192.0f;
    float var = fmaxf(Q / 8192.0f - mean * mean, 0.f);
    smean = mean; sinv = rsqrtf(var + 1e-5f);
  }
  __syncthreads();
  float mean = smean, inv = sinv;

  const float* xb = x + ((long)(b * 64) * 1024 + t) * 128;
  #pragma unroll
  for (int rr = 0; rr < 8; rr++) {
    int c = r0 + rr;
    f32x4 g4 = *(const f32x4*)(gp + c * 128 + f0);
    f32x4 b4 = *(const f32x4*)(bep + c * 128 + f0);
    f32x4 x4 = *(const f32x4*)(xb + (long)c * 131072 + f0);
    f32x4 o;
    o[0] = (acc[rr][0] - mean) * inv * g4[0] + b4[0] + x4[0];
    o[1] = (acc[rr][1] - mean) * inv * g4[1] + b4[1] + x4[1];
    o[2] = (acc[rr][2] - mean) * inv * g4[2] + b4[2] + x4[2];
    o[3] = (acc[rr][3] - mean) * inv * g4[3] + b4[3] + x4[3];
    *(f32x4*)(io + ((long)(b * 64 + c) * 1024 + t) * 128 + f0) = o;
  }
}

// ---------------------------------------------------------------------------
extern "C" void kernel_launch(void* const* d_in, const int* in_sizes, int n_in,
                              void* d_out, int out_size, void* d_ws, size_t ws_size,
                              hipStream_t stream)
{
  const float* x   = (const float*)d_in[0];
  const float* Wq  = (const float*)d_in[1];
  const float* bq  = (const float*)d_in[2];
  const float* aq  = (const float*)d_in[3];
  const float* gq  = (const float*)d_in[4];
  const float* beq = (const float*)d_in[5];
  const float* Wk  = (const float*)d_in[6];
  const float* bk  = (const float*)d_in[7];
  const float* ak  = (const float*)d_in[8];
  const float* gk  = (const float*)d_in[9];
  const float* bek = (const float*)d_in[10];
  const float* Wv  = (const float*)d_in[11];
  const float* bv  = (const float*)d_in[12];
  const float* av  = (const float*)d_in[13];
  const float* gv  = (const float*)d_in[14];
  const float* bev = (const float*)d_in[15];
  const float* Wp  = (const float*)d_in[16];
  const float* bp  = (const float*)d_in[17];
  const float* ap  = (const float*)d_in[18];
  const float* gp  = (const float*)d_in[19];
  const float* bep = (const float*)d_in[20];
  float* out = (float*)d_out;

  char* ws = (char*)d_ws;
  size_t off = 0;
  auto alloc = [&](size_t n) { size_t o = off; off += (n + 255) & ~(size_t)255; return o; };

  float* ball = (float*)(ws + alloc(96 * 4));
  float* aall = (float*)(ws + alloc(96 * 4));
  float* Wps  = (float*)(ws + alloc(4096 * 4));
  unsigned short* Wbf = (unsigned short*)(ws + alloc(6144 * 2));
  unsigned short* gba = (unsigned short*)(ws + alloc(12288 * 2));
  unsigned short* bba = (unsigned short*)(ws + alloc(12288 * 2));
  unsigned short* qf  = (unsigned short*)(ws + alloc((size_t)16 * 1024 * 512 * 2));
  unsigned short* kf  = (unsigned short*)(ws + alloc((size_t)16 * 1024 * 512 * 2));
  unsigned short* vf  = (unsigned short*)(ws + alloc((size_t)16 * 1024 * 2048 * 2));
  unsigned short* vfT = (unsigned short*)(ws + alloc((size_t)16 * 1024 * 2048 * 2));
  unsigned short* P   = vf;   // vf dead after transpose; P (32 MB) in vf lower half
  unsigned short* ofA = qf;   // attn_out bf16: z<8 in dead qf+kf (32 MB contiguous)
  unsigned short* ofB = (unsigned short*)((char*)vf + (size_t)32 * 1024 * 1024);

  prep_kernel<<<137, 256, 0, stream>>>(bq, aq, bk, ak, bv, av, Wp,
                                       Wq, Wk, Wv, gq, gk, gv, beq, bek, bev,
                                       ball, aall, Wps, Wbf, gba, bba);

  qkv_mfma<<<dim3(1024, 4), 256, 0, stream>>>(
      x, Wbf, ball, aall, gba, bba, qf, kf, vf);

  transpose_v<<<dim3(32, 16, 16), 256, 0, stream>>>(vf, vfT);

  // S = scale * Q K^T -> P (bf16)
  gemm_bt<<<dim3(8, 8, 16), 256, 0, stream>>>(
      qf, kf, P, P + (long)8 * 1024 * 1024, 1024, 1024, 512,
      (long)1024 * 512, (long)1024 * 512, (long)1024 * 1024,
      0.04419417382f /* 1/sqrt(512) */);

  softmax_kernel<<<dim3(1024, 16), 256, 0, stream>>>(P);

  // attn_out = P @ V -> bf16 row-major of[z][t][dv]
  gemm_bt<<<dim3(16, 8, 16), 256, 0, stream>>>(
      P, vfT, ofA, ofB, 1024, 2048, 1024,
      (long)1024 * 1024, (long)2048 * 1024, (long)1024 * 2048, 1.0f);

  // proj + norm + residual
  proj_kernel<<<dim3(1024, 4), 256, 0, stream>>>(out, ofA, ofB, Wps, bp, ap, gp, bep, x);
}

// Round 5
// 504.616 us; speedup vs baseline: 1.2998x; 1.0263x over previous
//
#include <hip/hip_runtime.h>
#include <hip/hip_bf16.h>

typedef __attribute__((ext_vector_type(4))) float f32x4;
typedef __attribute__((ext_vector_type(8))) short short8;

__device__ __forceinline__ float bf2f(unsigned short u){
  union { unsigned u32; float f; } v; v.u32 = ((unsigned)u) << 16; return v.f;
}
__device__ __forceinline__ unsigned short f2bf(float f){
  union { float f; unsigned u; } v; v.f = f;
  unsigned x = v.u;
  unsigned r = x + 0x7fffu + ((x >> 16) & 1u);
  return (unsigned short)(r >> 16);
}
// packed f32x2 -> bf16x2 (RNE), gfx950 HW instruction. lo16 = cvt(a), hi16 = cvt(b).
__device__ __forceinline__ unsigned cvtpk(float a, float b){
  unsigned r;
  asm("v_cvt_pk_bf16_f32 %0, %1, %2" : "=v"(r) : "v"(a), "v"(b));
  return r;
}

// async global->LDS, 16B per lane. LDS dest is wave-uniform base + lane*16.
__device__ __forceinline__ void gload_lds16(const unsigned short* g, unsigned short* l) {
  __builtin_amdgcn_global_load_lds(
      (const __attribute__((address_space(1))) unsigned int*)g,
      (__attribute__((address_space(3))) unsigned int*)l, 16, 0, 0);
}

// ---------------------------------------------------------------------------
// K0: prep — ball[96], aall[96] (row order: 0..15 q (h*4+o), 16..31 k,
// 32..95 v (h*16+o)); Wps[c][o] = Wp[o][c]; bf16 Wbf[96][64];
// bf16 gba/bba[96][128] (gamma/beta in the same row order).
// ---------------------------------------------------------------------------
__global__ __launch_bounds__(256) void prep_kernel(
    const float* bq, const float* aq, const float* bk, const float* ak,
    const float* bv, const float* av, const float* Wp,
    const float* Wq, const float* Wk, const float* Wv,
    const float* gq, const float* gk, const float* gv,
    const float* beq, const float* bek, const float* bev,
    float* ball, float* aall, float* Wps,
    unsigned short* Wbf, unsigned short* gba, unsigned short* bba)
{
  int idx = blockIdx.x * 256 + threadIdx.x;
  if (idx < 96) {
    int j = idx;
    float b, a;
    if (j < 16)      { b = bq[j];      a = aq[j >> 2]; }
    else if (j < 32) { b = bk[j - 16]; a = ak[(j - 16) >> 2]; }
    else             { b = bv[j - 32]; a = av[(j - 32) >> 4]; }
    ball[j] = b; aall[j] = a;
  } else if (idx < 4192) {
    int r = idx - 96; int o = r >> 6, c = r & 63;
    Wps[c * 64 + o] = Wp[o * 64 + c];
  } else if (idx < 10336) {
    int r = idx - 4192; int j = r >> 6, c = r & 63;
    float w = (j < 16) ? Wq[j * 64 + c] : (j < 32) ? Wk[(j - 16) * 64 + c]
                                                   : Wv[(j - 32) * 64 + c];
    Wbf[j * 64 + c] = f2bf(w);
  } else if (idx < 22624) {
    int r = idx - 10336; int j = r >> 7, f = r & 127;
    float g = (j < 16) ? gq[j * 128 + f] : (j < 32) ? gk[(j - 16) * 128 + f]
                                                    : gv[(j - 32) * 128 + f];
    gba[j * 128 + f] = f2bf(g);
  } else if (idx < 34912) {
    int r = idx - 22624; int j = r >> 7, f = r & 127;
    float be = (j < 16) ? beq[j * 128 + f] : (j < 32) ? bek[(j - 16) * 128 + f]
                                                      : bev[(j - 32) * 128 + f];
    bba[j * 128 + f] = f2bf(be);
  }
}

// ---------------------------------------------------------------------------
// K1: MFMA QKV, one t per block (grid 1024 x 4). 4 waves = 2 row-groups x
// 2 col-groups; wave computes 48 j-rows x 64 f-cols.
// SWAPPED MFMA operands: acc = mfma(xfrag, wfrag) -> thread holds
// (j = l15 fixed per mt, f = colg*64 + nt*16 + quad*4 + r: 4 CONSECUTIVE f).
// Consecutive-f registers enable v_cvt_pk_bf16_f32 packing everywhere and
// cut the 16-lane row reduction to 2 shfl_xor (16,32).
// yl stash double-buffered (one per row-group) -> 3 barriers total.
// Occupancy is REGISTER-bound: do NOT force >3 waves/EU (R2: spill = 3x HBM).
// ---------------------------------------------------------------------------
__global__ __launch_bounds__(256, 3) void qkv_mfma(
    const float* __restrict__ x,
    const unsigned short* __restrict__ Wbf,
    const float* __restrict__ ball, const float* __restrict__ aall,
    const unsigned short* __restrict__ gba, const unsigned short* __restrict__ bba,
    unsigned short* __restrict__ qf, unsigned short* __restrict__ kf,
    unsigned short* __restrict__ vf)
{
  __shared__ unsigned short upool[2 * 48 * 136];  // xl 16KB; yl[2] 2x13KB
  __shared__ float partS[4][96], partQ[4][96];
  __shared__ float gm[12], gi[12];
  __shared__ float bias_l[96], a_l[96];

  int tid = threadIdx.x;
  int t = blockIdx.x, b = blockIdx.y;
  int lane = tid & 63, wave = tid >> 6;
  int l15 = lane & 15, quad = lane >> 4;
  int rowg = wave >> 1, colg = wave & 1;

  if (tid < 96) { bias_l[tid] = ball[tid]; a_l[tid] = aall[tid]; }

  // ---- W fragments (B operand): lane l15 -> col j, quad -> k-chunk ----
  short8 wfr[3][2];
  #pragma unroll
  for (int mt = 0; mt < 3; mt++) {
    int row = (rowg * 3 + mt) * 16 + l15;
    #pragma unroll
    for (int ks = 0; ks < 2; ks++)
      wfr[mt][ks] = *(const short8*)(Wbf + row * 64 + ks * 32 + quad * 8);
  }

  // ---- stage X(b,:,t,:) -> xl[f][c] bf16, swizzled; cvt_pk + v_perm ----
  unsigned short* xl = upool;
  {
    float2 v[16];
    #pragma unroll
    for (int it = 0; it < 2; it++) {
      int item = it * 256 + tid;      // 512 items: 8 cb x 64 f-pairs
      int cb = item >> 6;
      int np = item & 63;
      const float* gp = x + ((long)(b * 64 + cb * 8) * 1024 + t) * 128 + np * 2;
      #pragma unroll
      for (int w = 0; w < 8; w++)
        v[it * 8 + w] = *(const float2*)(gp + (long)w * 131072);
    }
    #pragma unroll
    for (int it = 0; it < 2; it++) {
      int item = it * 256 + tid;
      int cb = item >> 6;
      int np = item & 63;
      int n = np * 2;
      unsigned pk[8];
      #pragma unroll
      for (int w = 0; w < 8; w++)
        pk[w] = cvtpk(v[it * 8 + w].x, v[it * 8 + w].y);  // lo=row n, hi=row n+1
      union { unsigned u[4]; short8 s; } lo, hi;
      #pragma unroll
      for (int k = 0; k < 4; k++) {
        lo.u[k] = __builtin_amdgcn_perm(pk[2 * k + 1], pk[2 * k], 0x05040100u);
        hi.u[k] = __builtin_amdgcn_perm(pk[2 * k + 1], pk[2 * k], 0x07060302u);
      }
      int perm_s = cb ^ (np & 7);     // key = (n>>1)&7, same for n and n+1
      *(short8*)&xl[n * 64 + perm_s * 8]       = lo.s;
      *(short8*)&xl[(n + 1) * 64 + perm_s * 8] = hi.s;
    }
  }
  __syncthreads();

  // ---- MFMA (swapped): acc[mt][nt] -> D[row=f-local][col=j-local] ----
  f32x4 acc[3][4];
  #pragma unroll
  for (int mt = 0; mt < 3; mt++)
    #pragma unroll
    for (int nt = 0; nt < 4; nt++)
      acc[mt][nt] = {0.f, 0.f, 0.f, 0.f};

  int nb = colg * 64;
  #pragma unroll
  for (int ks = 0; ks < 2; ks++)
    #pragma unroll
    for (int nt = 0; nt < 4; nt++) {
      int n = nb + nt * 16 + l15;
      int perm_s = (ks * 4 + quad) ^ ((n >> 1) & 7);
      short8 xfrag = *(const short8*)&xl[n * 64 + perm_s * 8];
      #pragma unroll
      for (int mt = 0; mt < 3; mt++)
        acc[mt][nt] = __builtin_amdgcn_mfma_f32_16x16x32_bf16(
            xfrag, wfr[mt][ks], acc[mt][nt], 0, 0, 0);
    }

  // ---- bias + PReLU + per-j sums (within-thread over 16 f + 2 shfl) ----
  #pragma unroll
  for (int mt = 0; mt < 3; mt++) {
    int j = (rowg * 3 + mt) * 16 + l15;
    float bb = bias_l[j], aa = a_l[j];
    float s = 0.f, q2 = 0.f;
    #pragma unroll
    for (int nt = 0; nt < 4; nt++)
      #pragma unroll
      for (int r = 0; r < 4; r++) {
        float v = acc[mt][nt][r] + bb;
        v = v > 0.f ? v : aa * v;
        acc[mt][nt][r] = v;
        s += v; q2 += v * v;
      }
    s  += __shfl_xor(s, 16, 64);  s += __shfl_xor(s, 32, 64);
    q2 += __shfl_xor(q2, 16, 64); q2 += __shfl_xor(q2, 32, 64);
    if (quad == 0) { partS[wave][j] = s; partQ[wave][j] = q2; }
  }
  __syncthreads();   // xl reads done; partS/Q complete

  // ---- group stats (tid<12) runs concurrently with the stash below ----
  if (tid < 12) {
    int g = tid;
    int r0 = (g < 4) ? g * 4 : (g < 8) ? 16 + (g - 4) * 4 : 32 + (g - 8) * 16;
    int nr = (g < 8) ? 4 : 16;
    int rw = (r0 < 48) ? 0 : 2;         // wave base of the owning row-group
    float S = 0.f, Q = 0.f;
    for (int w2 = 0; w2 < 2; w2++)
      for (int r = 0; r < nr; r++) { S += partS[rw + w2][r0 + r]; Q += partQ[rw + w2][r0 + r]; }
    float cnt = (float)(nr * 128);
    float mean = S / cnt;
    float var = fmaxf(Q / cnt - mean * mean, 0.f);
    gm[g] = mean;
    gi[g] = rsqrtf(var + 1e-5f);
  }

  // ---- stash: each row-group packs its 48 rows into its own yl buffer ----
  unsigned short* ylw = upool + rowg * (48 * 136);
  #pragma unroll
  for (int mt = 0; mt < 3; mt++) {
    int jrel = mt * 16 + l15;
    #pragma unroll
    for (int nt = 0; nt < 4; nt++) {
      int f = nb + nt * 16 + quad * 4;
      union { unsigned u[2]; uint2 u2; } p;
      p.u[0] = cvtpk(acc[mt][nt][0], acc[mt][nt][1]);
      p.u[1] = cvtpk(acc[mt][nt][2], acc[mt][nt][3]);
      *(uint2*)&ylw[jrel * 136 + f] = p.u2;
    }
  }
  __syncthreads();   // yl[2] + gm/gi ready

  // ---- normalize + gamma/beta + coalesced bf16 stores (no more barriers) --
  int ch = tid & 15, jrow = tid >> 4;
  #pragma unroll
  for (int half = 0; half < 2; half++) {
    const unsigned short* ylr = upool + half * (48 * 136);
    #pragma unroll
    for (int itj = 0; itj < 3; itj++) {
      int jrel = itj * 16 + jrow;
      int j = half * 48 + jrel;
      int f = ch * 8;
      short8 y8 = *(const short8*)&ylr[jrel * 136 + f];
      int g = (j < 16) ? (j >> 2) : (j < 32) ? 4 + ((j - 16) >> 2) : 8 + ((j - 32) >> 4);
      float mean = gm[g], inv = gi[g];
      unsigned short* dst;
      if (j < 16) {
        int h = j >> 2, o = j & 3;
        dst = qf + (((long)(h * 4 + b) * 1024 + t) * 512 + o * 128 + f);
      } else if (j < 32) {
        int jo = j - 16; int h = jo >> 2, o = jo & 3;
        dst = kf + (((long)(h * 4 + b) * 1024 + t) * 512 + o * 128 + f);
      } else {
        int jo = j - 32; int h = jo >> 4, o = jo & 15;
        dst = vf + (((long)(h * 4 + b) * 1024 + t) * 2048 + o * 128 + f);
      }
      short8 g8 = *(const short8*)(gba + j * 128 + f);
      short8 b8 = *(const short8*)(bba + j * 128 + f);
      float o_[8];
      #pragma unroll
      for (int i = 0; i < 8; i++)
        o_[i] = (bf2f((unsigned short)y8[i]) - mean) * inv
                * bf2f((unsigned short)g8[i]) + bf2f((unsigned short)b8[i]);
      union { unsigned u[4]; short8 s; } ou;
      #pragma unroll
      for (int i = 0; i < 4; i++)
        ou.u[i] = cvtpk(o_[2 * i], o_[2 * i + 1]);
      *(short8*)dst = ou.s;
    }
  }
}

// ---------------------------------------------------------------------------
// K2: transpose vf[n][t][dv] -> vfT[n][dv][t]  (64x64 tiles via LDS, bf16)
// ---------------------------------------------------------------------------
__global__ __launch_bounds__(256) void transpose_v(
    const unsigned short* __restrict__ vf, unsigned short* __restrict__ vfT)
{
  __shared__ unsigned short tile[64][65];
  int n = blockIdx.z;
  int d0 = blockIdx.x * 64, t0 = blockIdx.y * 64;
  int tid = threadIdx.x;
  int cr = tid >> 4, cc = (tid & 15) * 4;

  const unsigned short* src = vf + ((long)n * 1024 + t0) * 2048 + d0;
  #pragma unroll
  for (int i = 0; i < 4; i++) {
    int r = cr + i * 16;   // t-local
    ushort4 u = *(const ushort4*)(src + (long)r * 2048 + cc);
    tile[r][cc + 0] = u.x; tile[r][cc + 1] = u.y;
    tile[r][cc + 2] = u.z; tile[r][cc + 3] = u.w;
  }
  __syncthreads();
  unsigned short* dst = vfT + ((long)n * 2048 + d0) * 1024 + t0;
  #pragma unroll
  for (int i = 0; i < 4; i++) {
    int r = cr + i * 16;   // d-local
    ushort4 u;
    u.x = tile[cc + 0][r]; u.y = tile[cc + 1][r];
    u.z = tile[cc + 2][r]; u.w = tile[cc + 3][r];
    *(ushort4*)(dst + (long)r * 1024 + cc) = u;
  }
}

// ---------------------------------------------------------------------------
// K3: batched GEMM, D = scale * A B^T (both k-contiguous), bf16 in/out.
// 128x128 tile, BK=64, 4 waves, 32 MFMA/iter. global_load_lds dwordx4 into
// linear [128][64]-ushort LDS; slot swizzle key row&7; source pre-swizzled.
// Epilogue stages C in LDS and stores full 64B lines. Output bf16 row-major,
// batch z split across two base pointers. XCD-aware bijective block swizzle.
// ---------------------------------------------------------------------------
__global__ __launch_bounds__(256) void gemm_bt(
    const unsigned short* __restrict__ A, const unsigned short* __restrict__ B,
    unsigned short* __restrict__ CbA, unsigned short* __restrict__ CbB,
    int M, int N, int K, long sA, long sB, long sC, float scale)
{
  __shared__ unsigned short smem[128 * 136];   // As[128*64] Bs[128*64]; C staging
  unsigned short* As = smem;
  unsigned short* Bs = smem + 128 * 64;
  int tid = threadIdx.x;

  // ---- XCD-aware bijective swizzle of the linearized block id ----
  int gx = gridDim.x, gy = gridDim.y;
  int bid = blockIdx.x + gx * (blockIdx.y + gy * blockIdx.z);
  int nwg = gx * gy * (int)gridDim.z;     // 1024 (QK) / 2048 (PV): % 8 == 0
  int cpx = nwg >> 3;
  int tile = (bid & 7) * cpx + (bid >> 3);
  int tx = tile % gx, trem = tile / gx;
  int ty = trem % gy, z = trem / gy;

  int m0 = ty * 128, n0 = tx * 128;
  const unsigned short* Ab = A + (long)z * sA + (long)m0 * K;
  const unsigned short* Bb = B + (long)z * sB + (long)n0 * K;
  int lane = tid & 63, wave = tid >> 6;
  int wm = (wave >> 1) * 64, wn = (wave & 1) * 64;
  int l15 = lane & 15, quad = lane >> 4;

  f32x4 acc[4][4];
  #pragma unroll
  for (int i = 0; i < 4; i++)
    #pragma unroll
    for (int j = 0; j < 4; j++) acc[i][j] = {0.f, 0.f, 0.f, 0.f};

  // staging: one gload call = 64 lanes x 16B = 8 rows of 128B.
  int srow8 = lane >> 3;
  int sck   = (lane & 7) ^ srow8;        // R%8==0 -> row&7 == lane>>3

  for (int k0 = 0; k0 < K; k0 += 64) {
    #pragma unroll
    for (int it = 0; it < 4; it++) {
      int R = it * 32 + wave * 8;        // 4 its x 4 waves x 8 rows = 128
      int row = R + srow8;
      gload_lds16(Ab + (long)row * K + k0 + sck * 8, &As[R * 64]);
      gload_lds16(Bb + (long)row * K + k0 + sck * 8, &Bs[R * 64]);
    }
    __syncthreads();                     // drains vmcnt before ds_read
    #pragma unroll
    for (int ks = 0; ks < 2; ks++) {
      short8 af[4], bfr[4];
      #pragma unroll
      for (int i = 0; i < 4; i++) {
        int row = wm + i * 16 + l15;
        af[i] = *(const short8*)&As[row * 64 + ((ks * 4 + quad) ^ (row & 7)) * 8];
      }
      #pragma unroll
      for (int j = 0; j < 4; j++) {
        int row = wn + j * 16 + l15;
        bfr[j] = *(const short8*)&Bs[row * 64 + ((ks * 4 + quad) ^ (row & 7)) * 8];
      }
      #pragma unroll
      for (int i = 0; i < 4; i++)
        #pragma unroll
        for (int j = 0; j < 4; j++)
          acc[i][j] = __builtin_amdgcn_mfma_f32_16x16x32_bf16(af[i], bfr[j], acc[i][j], 0, 0, 0);
    }
    __syncthreads();
  }

  // ---- epilogue: C tile -> LDS (bf16, pitch 136) -> full-line stores ----
  #pragma unroll
  for (int i = 0; i < 4; i++)
    #pragma unroll
    for (int j = 0; j < 4; j++) {
      int row0 = wm + i * 16 + quad * 4;
      int col = wn + j * 16 + l15;
      #pragma unroll
      for (int r = 0; r < 4; r++)
        smem[(row0 + r) * 136 + col] = f2bf(acc[i][j][r] * scale);
    }
  __syncthreads();
  unsigned short* Cz = (z < 8) ? (CbA + (long)z * sC) : (CbB + (long)(z - 8) * sC);
  #pragma unroll
  for (int it = 0; it < 8; it++) {
    int chunk = it * 256 + tid;          // 2048 chunks of 8 ushorts
    int row = chunk >> 4, c8 = (chunk & 15) * 8;
    *(short8*)(Cz + (long)(m0 + row) * N + n0 + c8) = *(const short8*)&smem[row * 136 + c8];
  }
}

// ---------------------------------------------------------------------------
// K4: in-place row softmax on P[z][row][0..1024) (bf16, already scaled)
// ---------------------------------------------------------------------------
__global__ __launch_bounds__(256) void softmax_kernel(unsigned short* __restrict__ P)
{
  __shared__ float red[4];
  __shared__ float bmax, bsum;
  int row = blockIdx.x, z = blockIdx.y, tid = threadIdx.x;
  unsigned short* p = P + ((long)z * 1024 + row) * 1024;
  ushort4 u = *(ushort4*)(p + tid * 4);
  float v0 = bf2f(u.x), v1 = bf2f(u.y), v2 = bf2f(u.z), v3 = bf2f(u.w);

  float m = fmaxf(fmaxf(v0, v1), fmaxf(v2, v3));
  #pragma unroll
  for (int s = 1; s <= 32; s <<= 1) m = fmaxf(m, __shfl_xor(m, s, 64));
  if ((tid & 63) == 0) red[tid >> 6] = m;
  __syncthreads();
  if (tid == 0) bmax = fmaxf(fmaxf(red[0], red[1]), fmaxf(red[2], red[3]));
  __syncthreads();
  m = bmax;

  float e0 = __expf(v0 - m), e1 = __expf(v1 - m), e2 = __expf(v2 - m), e3 = __expf(v3 - m);
  float s = e0 + e1 + e2 + e3;
  #pragma unroll
  for (int k = 1; k <= 32; k <<= 1) s += __shfl_xor(s, k, 64);
  if ((tid & 63) == 0) red[tid >> 6] = s;
  __syncthreads();
  if (tid == 0) bsum = red[0] + red[1] + red[2] + red[3];
  __syncthreads();
  float inv = 1.0f / bsum;

  u.x = f2bf(e0 * inv); u.y = f2bf(e1 * inv);
  u.z = f2bf(e2 * inv); u.w = f2bf(e3 * inv);
  *(ushort4*)(p + tid * 4) = u;
}

// ---------------------------------------------------------------------------
// K5: proj (64x64) + bias + PReLU + ChannelNorm over (C,F) + gp/betap + x.
// Reads attn_out from bf16 of[z][t][dv] (z = h*4+b, split base pointers),
// writes fp32 d_out (b,c,t,f).
// ---------------------------------------------------------------------------
__global__ __launch_bounds__(256) void proj_kernel(
    float* __restrict__ io,
    const unsigned short* __restrict__ ofA, const unsigned short* __restrict__ ofB,
    const float* __restrict__ Wps,
    const float* __restrict__ bp, const float* __restrict__ ap,
    const float* __restrict__ gp, const float* __restrict__ bep,
    const float* __restrict__ x)
{
  __shared__ float xl[64 * 128];
  __shared__ float wl[64 * 64];
  __shared__ float redS[4], redQ[4];
  __shared__ float smean, sinv;

  int tid = threadIdx.x;
  int t = blockIdx.x, b = blockIdx.y;

  // stage attn_out (b, :, t, :) from of: 4 h-slices x 4KB contiguous bf16
  #pragma unroll
  for (int i = 0; i < 4; i++) {
    int chunk = i * 256 + tid;           // 1024 chunks of 8
    int h = chunk >> 8;
    int dvc = (chunk & 255) * 8;
    int z = h * 4 + b;
    const unsigned short* base =
        (z < 8) ? (ofA + (long)z * 2097152) : (ofB + (long)(z - 8) * 2097152);
    short8 v = *(const short8*)(base + (long)t * 2048 + dvc);
    int c = h * 16 + (dvc >> 7);
    int f = dvc & 127;
    #pragma unroll
    for (int e = 0; e < 8; e++) xl[c * 128 + f + e] = bf2f((unsigned short)v[e]);
  }
  #pragma unroll
  for (int i = 0; i < 4; i++) {
    int id = tid + i * 256;
    ((f32x4*)wl)[id] = ((const f32x4*)Wps)[id];
  }
  __syncthreads();

  int fblk = tid & 31, rblk = tid >> 5;
  int f0 = fblk * 4, r0 = rblk * 8;

  float acc[8][4];
  #pragma unroll
  for (int rr = 0; rr < 8; rr++)
    #pragma unroll
    for (int ff = 0; ff < 4; ff++) acc[rr][ff] = 0.f;

  for (int c = 0; c < 64; c++) {
    f32x4 xv = *(const f32x4*)&xl[c * 128 + f0];
    f32x4 w0 = *(const f32x4*)&wl[c * 64 + r0];
    f32x4 w1 = *(const f32x4*)&wl[c * 64 + r0 + 4];
    #pragma unroll
    for (int rr = 0; rr < 4; rr++) {
      #pragma unroll
      for (int ff = 0; ff < 4; ff++) {
        acc[rr][ff]     += w0[rr] * xv[ff];
        acc[rr + 4][ff] += w1[rr] * xv[ff];
      }
    }
  }

  float aval = ap[0];
  #pragma unroll
  for (int rr = 0; rr < 8; rr++) {
    float bb = bp[r0 + rr];
    #pragma unroll
    for (int ff = 0; ff < 4; ff++) {
      float v = acc[rr][ff] + bb;
      acc[rr][ff] = v > 0.f ? v : aval * v;
    }
  }

  float s = 0.f, sq = 0.f;
  #pragma unroll
  for (int rr = 0; rr < 8; rr++)
    #pragma unroll
    for (int ff = 0; ff < 4; ff++) { s += acc[rr][ff]; sq += acc[rr][ff] * acc[rr][ff]; }
  #pragma unroll
  for (int m = 1; m <= 32; m <<= 1) { s += __shfl_xor(s, m, 64); sq += __shfl_xor(sq, m, 64); }
  if ((tid & 63) == 0) { redS[tid >> 6] = s; redQ[tid >> 6] = sq; }
  __syncthreads();
  if (tid == 0) {
    float S = redS[0] + redS[1] + redS[2] + redS[3];
    float Q = redQ[0] + redQ[1] + redQ[2] + redQ[3];
    float mean = S / 8192.0f;
    float var = fmaxf(Q / 8192.0f - mean * mean, 0.f);
    smean = mean; sinv = rsqrtf(var + 1e-5f);
  }
  __syncthreads();
  float mean = smean, inv = sinv;

  const float* xb = x + ((long)(b * 64) * 1024 + t) * 128;
  #pragma unroll
  for (int rr = 0; rr < 8; rr++) {
    int c = r0 + rr;
    f32x4 g4 = *(const f32x4*)(gp + c * 128 + f0);
    f32x4 b4 = *(const f32x4*)(bep + c * 128 + f0);
    f32x4 x4 = *(const f32x4*)(xb + (long)c * 131072 + f0);
    f32x4 o;
    o[0] = (acc[rr][0] - mean) * inv * g4[0] + b4[0] + x4[0];
    o[1] = (acc[rr][1] - mean) * inv * g4[1] + b4[1] + x4[1];
    o[2] = (acc[rr][2] - mean) * inv * g4[2] + b4[2] + x4[2];
    o[3] = (acc[rr][3] - mean) * inv * g4[3] + b4[3] + x4[3];
    *(f32x4*)(io + ((long)(b * 64 + c) * 1024 + t) * 128 + f0) = o;
  }
}

// ---------------------------------------------------------------------------
extern "C" void kernel_launch(void* const* d_in, const int* in_sizes, int n_in,
                              void* d_out, int out_size, void* d_ws, size_t ws_size,
                              hipStream_t stream)
{
  const float* x   = (const float*)d_in[0];
  const float* Wq  = (const float*)d_in[1];
  const float* bq  = (const float*)d_in[2];
  const float* aq  = (const float*)d_in[3];
  const float* gq  = (const float*)d_in[4];
  const float* beq = (const float*)d_in[5];
  const float* Wk  = (const float*)d_in[6];
  const float* bk  = (const float*)d_in[7];
  const float* ak  = (const float*)d_in[8];
  const float* gk  = (const float*)d_in[9];
  const float* bek = (const float*)d_in[10];
  const float* Wv  = (const float*)d_in[11];
  const float* bv  = (const float*)d_in[12];
  const float* av  = (const float*)d_in[13];
  const float* gv  = (const float*)d_in[14];
  const float* bev = (const float*)d_in[15];
  const float* Wp  = (const float*)d_in[16];
  const float* bp  = (const float*)d_in[17];
  const float* ap  = (const float*)d_in[18];
  const float* gp  = (const float*)d_in[19];
  const float* bep = (const float*)d_in[20];
  float* out = (float*)d_out;

  char* ws = (char*)d_ws;
  size_t off = 0;
  auto alloc = [&](size_t n) { size_t o = off; off += (n + 255) & ~(size_t)255; return o; };

  float* ball = (float*)(ws + alloc(96 * 4));
  float* aall = (float*)(ws + alloc(96 * 4));
  float* Wps  = (float*)(ws + alloc(4096 * 4));
  unsigned short* Wbf = (unsigned short*)(ws + alloc(6144 * 2));
  unsigned short* gba = (unsigned short*)(ws + alloc(12288 * 2));
  unsigned short* bba = (unsigned short*)(ws + alloc(12288 * 2));
  unsigned short* qf  = (unsigned short*)(ws + alloc((size_t)16 * 1024 * 512 * 2));
  unsigned short* kf  = (unsigned short*)(ws + alloc((size_t)16 * 1024 * 512 * 2));
  unsigned short* vf  = (unsigned short*)(ws + alloc((size_t)16 * 1024 * 2048 * 2));
  unsigned short* vfT = (unsigned short*)(ws + alloc((size_t)16 * 1024 * 2048 * 2));
  unsigned short* P   = vf;   // vf dead after transpose; P (32 MB) in vf lower half
  unsigned short* ofA = qf;   // attn_out bf16: z<8 in dead qf+kf (32 MB contiguous)
  unsigned short* ofB = (unsigned short*)((char*)vf + (size_t)32 * 1024 * 1024);

  prep_kernel<<<137, 256, 0, stream>>>(bq, aq, bk, ak, bv, av, Wp,
                                       Wq, Wk, Wv, gq, gk, gv, beq, bek, bev,
                                       ball, aall, Wps, Wbf, gba, bba);

  qkv_mfma<<<dim3(1024, 4), 256, 0, stream>>>(
      x, Wbf, ball, aall, gba, bba, qf, kf, vf);

  transpose_v<<<dim3(32, 16, 16), 256, 0, stream>>>(vf, vfT);

  // S = scale * Q K^T -> P (bf16)
  gemm_bt<<<dim3(8, 8, 16), 256, 0, stream>>>(
      qf, kf, P, P + (long)8 * 1024 * 1024, 1024, 1024, 512,
      (long)1024 * 512, (long)1024 * 512, (long)1024 * 1024,
      0.04419417382f /* 1/sqrt(512) */);

  softmax_kernel<<<dim3(1024, 16), 256, 0, stream>>>(P);

  // attn_out = P @ V -> bf16 row-major of[z][t][dv]
  gemm_bt<<<dim3(16, 8, 16), 256, 0, stream>>>(
      P, vfT, ofA, ofB, 1024, 2048, 1024,
      (long)1024 * 1024, (long)2048 * 1024, (long)1024 * 2048, 1.0f);

  // proj + norm + residual
  proj_kernel<<<dim3(1024, 4), 256, 0, stream>>>(out, ofA, ofB, Wps, bp, ap, gp, bep, x);
}